// Round 2
// baseline (833.375 us; speedup 1.0000x reference)
//
#include <hip/hip_runtime.h>
#include <cstdint>

typedef __bf16 bf16x8 __attribute__((ext_vector_type(8)));
typedef float f32x4 __attribute__((ext_vector_type(4)));
typedef int v4i __attribute__((ext_vector_type(4)));

#define DI __device__ __forceinline__

constexpr int NTOK = 4096;   // B*S
constexpr int HID  = 1024;
constexpr int IMO  = 512;    // moe intermediate
constexpr int NEXP = 16;
constexpr int SHI  = 1024;   // shared intermediate

DI unsigned short f2bf(float f) {
  unsigned u = __float_as_uint(f);
  u = (u + 0x7fffu + ((u >> 16) & 1u)) >> 16;   // round-to-nearest-even
  return (unsigned short)u;
}
DI float bf2f(unsigned short b) { return __uint_as_float(((unsigned)b) << 16); }

// ---------------- init / prefix / scatter ----------------
__global__ void init_counts(int* __restrict__ counts) {
  if (threadIdx.x < NEXP) counts[threadIdx.x] = 0;
}

__global__ void prefix_kernel(const int* __restrict__ counts,
                              int* __restrict__ offsets, int* __restrict__ cursor) {
  if (threadIdx.x == 0 && blockIdx.x == 0) {
    int s = 0;
    for (int e = 0; e < NEXP; ++e) { offsets[e] = s; cursor[e] = s; s += counts[e]; }
    offsets[NEXP] = s;
  }
}

__global__ __launch_bounds__(256) void scatter_kernel(
    const int* __restrict__ topk_idx, int* __restrict__ cursor,
    int* __restrict__ perm, int* __restrict__ pos) {
  int i = blockIdx.x * 256 + threadIdx.x;   // over NTOK*4
  int e = topk_idx[i];
  int slot = atomicAdd(&cursor[e], 1);
  perm[slot] = i >> 2;
  pos[i] = slot;
}

// ---------------- gate (fp64 ranking) ----------------
__global__ __launch_bounds__(256) void gate_kernel(
    const float* __restrict__ x, const float* __restrict__ gw,
    const float* __restrict__ gb, int* __restrict__ topk_idx,
    float* __restrict__ topk_w, int* __restrict__ counts) {
  const int lane = threadIdx.x & 63;
  const int n = blockIdx.x * 4 + (threadIdx.x >> 6);
  const float* xr = x + (size_t)n * HID;
  float xv[16];
#pragma unroll
  for (int j = 0; j < 16; ++j) xv[j] = xr[j * 64 + lane];
  double sig[16], sfc[16];
#pragma unroll
  for (int e = 0; e < 16; ++e) {
    const float* wr = gw + e * HID;
    double acc = 0.0;
#pragma unroll
    for (int j = 0; j < 16; ++j) acc += (double)xv[j] * (double)wr[j * 64 + lane];
#pragma unroll
    for (int m = 32; m >= 1; m >>= 1) acc += __shfl_xor(acc, m, 64);
    double s = 1.0 / (1.0 + exp(-acc));
    sig[e] = s;
    sfc[e] = s + (double)gb[e];
  }
  // group score = sum of top-2 sfc within each group of 4
  double gs[4];
#pragma unroll
  for (int g = 0; g < 4; ++g) {
    double a = sfc[4 * g], b = sfc[4 * g + 1], c = sfc[4 * g + 2], d = sfc[4 * g + 3];
    double mab = fmax(a, b), mcd = fmax(c, d);
    double nab = fmin(a, b), ncd = fmin(c, d);
    gs[g] = fmax(mab, mcd) + fmax(fmax(nab, ncd), fmin(mab, mcd));
  }
  int g1 = 0; double b1 = gs[0];
#pragma unroll
  for (int g = 1; g < 4; ++g) if (gs[g] > b1) { b1 = gs[g]; g1 = g; }
  int g2 = 0; double b2 = -1e300;
#pragma unroll
  for (int g = 0; g < 4; ++g) if (g != g1 && gs[g] > b2) { b2 = gs[g]; g2 = g; }
  unsigned allow = (0xFu << (g1 * 4)) | (0xFu << (g2 * 4));
  unsigned chosen = 0;
  int idx[4]; double wv[4];
#pragma unroll
  for (int k = 0; k < 4; ++k) {
    double bv = -1e300, bw = 0.0; int bi = 0;
#pragma unroll
    for (int t = 0; t < 16; ++t) {
      bool ok = ((allow >> t) & 1u) && !((chosen >> t) & 1u);
      if (ok && sfc[t] > bv) { bv = sfc[t]; bw = sig[t]; bi = t; }
    }
    chosen |= (1u << bi);
    idx[k] = bi; wv[k] = bw;    // weights use sigmoid scores (pre-bias)
  }
  double s = wv[0] + wv[1] + wv[2] + wv[3] + 1e-20;
  if (lane == 0) {
#pragma unroll
    for (int k = 0; k < 4; ++k) {
      topk_idx[n * 4 + k] = idx[k];
      topk_w[n * 4 + k] = (float)(wv[k] / s * 2.5);
      atomicAdd(&counts[idx[k]], 1);
    }
  }
}

// ---------------- fp32 -> bf16 convert (all arrays, one launch) ----------------
__global__ __launch_bounds__(256) void convert_all(
    const float* __restrict__ x, const float* __restrict__ wg,
    const float* __restrict__ wu, const float* __restrict__ wd,
    const float* __restrict__ sg, const float* __restrict__ su,
    const float* __restrict__ sd,
    unsigned short* __restrict__ xb, unsigned short* __restrict__ wgb,
    unsigned short* __restrict__ wub, unsigned short* __restrict__ wdb,
    unsigned short* __restrict__ sgb, unsigned short* __restrict__ sub,
    unsigned short* __restrict__ sdb) {
  long g = (long)blockIdx.x * 256 + threadIdx.x;   // float4 index, total 8126464
  const float* s; unsigned short* d; long o;
  if      (g < 1048576L) { s = x;  d = xb;  o = g; }
  else if (g < 3145728L) { s = wg; d = wgb; o = g - 1048576L; }
  else if (g < 5242880L) { s = wu; d = wub; o = g - 3145728L; }
  else if (g < 7340032L) { s = wd; d = wdb; o = g - 5242880L; }
  else if (g < 7602176L) { s = sg; d = sgb; o = g - 7340032L; }
  else if (g < 7864320L) { s = su; d = sub; o = g - 7602176L; }
  else                   { s = sd; d = sdb; o = g - 7864320L; }
  float4 v = ((const float4*)s)[o];
  ushort4 r;
  r.x = f2bf(v.x); r.y = f2bf(v.y); r.z = f2bf(v.z); r.w = f2bf(v.w);
  ((ushort4*)d)[o] = r;
}

// ---------------- bf16 MFMA GEMM: C = A @ B^T (B stored [out,in]) ----------------
// 128x128 tile, BK=32, 4 waves (2x2), 16x16x32 MFMA, reg-staged double-buffered LDS.
// GU: fused gate+up (two B matrices, silu(g)*u epilogue, bf16 out).
// GATHER: A rows indirected through perm (routed gate/up).
// ROUTED: per-expert blocks (grid.x = 16*32), M = counts[e], rows offset by offsets[e].
template <bool GU, bool GATHER, bool ROUTED, typename OutT>
__global__ __launch_bounds__(256) void gemm_bt(
    const unsigned short* __restrict__ A, const unsigned short* __restrict__ B0,
    const unsigned short* __restrict__ B1, void* __restrict__ Cout,
    int M_, int K, int ldc, long eStrideB,
    const int* __restrict__ counts, const int* __restrict__ offsets,
    const int* __restrict__ perm) {
  int e = 0, mt = blockIdx.x, cnt = M_, off = 0;
  if (ROUTED) {
    e = blockIdx.x >> 5; mt = blockIdx.x & 31;
    cnt = counts[e]; off = offsets[e];
    if (mt * 128 >= cnt) return;
  }
  const int n0 = blockIdx.y * 128;
  const unsigned short* Bg = B0 + (ROUTED ? (long)e * eStrideB : 0L);
  const unsigned short* Bu = GU ? (B1 + (ROUTED ? (long)e * eStrideB : 0L)) : nullptr;

  const int tid = threadIdx.x;
  const int lane = tid & 63;
  const int wid = tid >> 6;
  const int wm = (wid >> 1) * 64, wn = (wid & 1) * 64;

  constexpr int BUFSH = GU ? 12288 : 8192;   // shorts per buffer
  __shared__ __align__(16) unsigned short lds[2 * BUFSH];

  // staging: chunk i = tid + j*256; row = i&127, kc = i>>7; LDS elem = i*8 (linear)
  const unsigned short* aP[2]; const unsigned short* gP[2]; const unsigned short* uP[2];
  int ldsOff[2];
#pragma unroll
  for (int j = 0; j < 2; ++j) {
    int i = tid + j * 256;
    int row = i & 127, kc = i >> 7;
    ldsOff[j] = i * 8;
    int am = mt * 128 + row;
    long ar;
    if (GATHER)      ar = perm[off + (am < cnt ? am : cnt - 1)];
    else if (ROUTED) ar = off + (am < cnt ? am : cnt - 1);
    else             ar = (am < M_ ? am : M_ - 1);
    aP[j] = A + ar * (long)K + kc * 8;
    gP[j] = Bg + (long)(n0 + row) * K + kc * 8;
    if (GU) uP[j] = Bu + (long)(n0 + row) * K + kc * 8;
  }

  f32x4 accg[4][4];
  f32x4 accu[GU ? 4 : 1][GU ? 4 : 1];
#pragma unroll
  for (int a = 0; a < 4; ++a)
#pragma unroll
    for (int b = 0; b < 4; ++b) {
      accg[a][b] = f32x4{0.f, 0.f, 0.f, 0.f};
      if constexpr (GU) accu[a][b] = f32x4{0.f, 0.f, 0.f, 0.f};
    }

  v4i ra[2], rg[2], ru[2];
  auto LOAD = [&]() {
#pragma unroll
    for (int j = 0; j < 2; ++j) {
      ra[j] = *(const v4i*)aP[j]; aP[j] += 32;
      rg[j] = *(const v4i*)gP[j]; gP[j] += 32;
      if constexpr (GU) { ru[j] = *(const v4i*)uP[j]; uP[j] += 32; }
    }
  };
  auto STORE = [&](int buf) {
    unsigned short* d = lds + buf * BUFSH;
#pragma unroll
    for (int j = 0; j < 2; ++j) {
      *(v4i*)(d + ldsOff[j]) = ra[j];
      *(v4i*)(d + 4096 + ldsOff[j]) = rg[j];
      if constexpr (GU) *(v4i*)(d + 8192 + ldsOff[j]) = ru[j];
    }
  };

  const int r16 = lane & 15, kc4 = lane >> 4;
  auto COMPUTE = [&](int buf) {
    const unsigned short* bA = lds + buf * BUFSH;
    const unsigned short* bG = bA + 4096;
    const unsigned short* bU = bA + 8192;
    bf16x8 af[4], gf[4], uf[4];
#pragma unroll
    for (int mi = 0; mi < 4; ++mi)
      af[mi] = *(const bf16x8*)(bA + kc4 * 1024 + (wm + mi * 16 + r16) * 8);
#pragma unroll
    for (int ni = 0; ni < 4; ++ni) {
      gf[ni] = *(const bf16x8*)(bG + kc4 * 1024 + (wn + ni * 16 + r16) * 8);
      if constexpr (GU)
        uf[ni] = *(const bf16x8*)(bU + kc4 * 1024 + (wn + ni * 16 + r16) * 8);
    }
#pragma unroll
    for (int mi = 0; mi < 4; ++mi)
#pragma unroll
      for (int ni = 0; ni < 4; ++ni) {
        accg[mi][ni] = __builtin_amdgcn_mfma_f32_16x16x32_bf16(af[mi], gf[ni], accg[mi][ni], 0, 0, 0);
        if constexpr (GU)
          accu[mi][ni] = __builtin_amdgcn_mfma_f32_16x16x32_bf16(af[mi], uf[ni], accu[mi][ni], 0, 0, 0);
      }
  };

  const int NT = K >> 5;
  LOAD();
  STORE(0);
  __syncthreads();
  int cur = 0;
  for (int t = 0; t < NT; ++t) {
    bool more = (t + 1 < NT);
    if (more) LOAD();          // global loads for t+1 hide under compute
    COMPUTE(cur);
    if (more) STORE(cur ^ 1);
    __syncthreads();
    cur ^= 1;
  }

  // epilogue: C layout col=lane&15, row=(lane>>4)*4+reg  [m89-verified]
#pragma unroll
  for (int mi = 0; mi < 4; ++mi)
#pragma unroll
    for (int ni = 0; ni < 4; ++ni)
#pragma unroll
      for (int j = 0; j < 4; ++j) {
        int r = wm + mi * 16 + kc4 * 4 + j;
        int gr = mt * 128 + r;
        bool okRow = ROUTED ? (gr < cnt) : (gr < M_);
        if (okRow) {
          long crow = (ROUTED ? (long)off : 0L) + gr;
          int c = n0 + wn + ni * 16 + r16;
          if constexpr (GU) {
            float g = accg[mi][ni][j], u = accu[mi][ni][j];
            float sg = g / (1.f + __expf(-g));       // silu
            ((unsigned short*)Cout)[crow * ldc + c] = f2bf(sg * u);
          } else if constexpr (sizeof(OutT) == 2) {
            ((unsigned short*)Cout)[crow * ldc + c] = f2bf(accg[mi][ni][j]);
          } else {
            ((float*)Cout)[crow * ldc + c] = accg[mi][ni][j];
          }
        }
      }
}

// ---------------- final combine: out = x + shared(in d_out) + sum_k w_k*yout ----------------
__global__ __launch_bounds__(256) void combine_kernel(
    const float* __restrict__ x, const float* __restrict__ sh,
    const unsigned short* __restrict__ yout, const float* __restrict__ tw,
    const int* __restrict__ pos, float* __restrict__ out) {
  int n = blockIdx.x;                  // one block per token
  int h4 = threadIdx.x << 2;           // 256 threads * 4 floats = 1024
  float4 xv = *(const float4*)(x + (long)n * HID + h4);
  float4 sv = *(const float4*)(sh + (long)n * HID + h4);   // shared-expert result (read before write)
  float a0 = xv.x + sv.x, a1 = xv.y + sv.y, a2 = xv.z + sv.z, a3 = xv.w + sv.w;
#pragma unroll
  for (int k = 0; k < 4; ++k) {
    float w = tw[n * 4 + k];
    long slot = pos[n * 4 + k];
    ushort4 yv = *(const ushort4*)(yout + slot * HID + h4);
    a0 += w * bf2f(yv.x); a1 += w * bf2f(yv.y);
    a2 += w * bf2f(yv.z); a3 += w * bf2f(yv.w);
  }
  float4 o; o.x = a0; o.y = a1; o.z = a2; o.w = a3;
  *(float4*)(out + (long)n * HID + h4) = o;
}

// ---------------- launch ----------------
extern "C" void kernel_launch(void* const* d_in, const int* in_sizes, int n_in,
                              void* d_out, int out_size, void* d_ws, size_t ws_size,
                              hipStream_t stream) {
  (void)in_sizes; (void)n_in; (void)out_size; (void)ws_size;
  const float* x   = (const float*)d_in[0];
  const float* gw  = (const float*)d_in[1];
  const float* gb  = (const float*)d_in[2];
  const float* Wg  = (const float*)d_in[3];
  const float* Wu  = (const float*)d_in[4];
  const float* Wd  = (const float*)d_in[5];
  const float* Wsg = (const float*)d_in[6];
  const float* Wsu = (const float*)d_in[7];
  const float* Wsd = (const float*)d_in[8];
  float* out = (float*)d_out;

  // ---- workspace layout (fixed round-1 overlap: big buffers start at 512 KiB) ----
  char* w = (char*)d_ws;
  int*   counts   = (int*)(w + 0);                    // 64 B
  int*   cursor   = (int*)(w + 64);                   // 64 B
  int*   offsets  = (int*)(w + 128);                  // 128 B (17 ints)
  int*   topk_idx = (int*)(w + 256);                  // 65536 B  [256, 65792)
  float* topk_w   = (float*)(w + 256 + 65536);        // 65536 B  [65792, 131328)
  int*   perm     = (int*)(w + 256 + 131072);         // 65536 B  [131328, 196864)
  int*   pos      = (int*)(w + 256 + 196608);         // 65536 B  [196864, 262400)
  size_t o = 524288;                                  // big buffers from 512 KiB
  unsigned short* xb   = (unsigned short*)(w + o); o += (size_t)NTOK * HID * 2;       // 8 MB
  unsigned short* WgB  = (unsigned short*)(w + o); o += (size_t)NEXP * IMO * HID * 2; // 16 MB
  unsigned short* WuB  = (unsigned short*)(w + o); o += (size_t)NEXP * IMO * HID * 2; // 16 MB
  unsigned short* WdB  = (unsigned short*)(w + o); o += (size_t)NEXP * HID * IMO * 2; // 16 MB
  unsigned short* WsgB = (unsigned short*)(w + o); o += (size_t)SHI * HID * 2;        // 2 MB
  unsigned short* WsuB = (unsigned short*)(w + o); o += (size_t)SHI * HID * 2;        // 2 MB
  unsigned short* WsdB = (unsigned short*)(w + o); o += (size_t)HID * SHI * 2;        // 2 MB
  unsigned short* act  = (unsigned short*)(w + o); o += (size_t)NTOK * 4 * IMO * 2;   // 16 MB
  unsigned short* yout = (unsigned short*)(w + o); o += (size_t)NTOK * 4 * HID * 2;   // 32 MB
  unsigned short* sact = (unsigned short*)(w + o); o += (size_t)NTOK * SHI * 2;       // 8 MB
  // total ws use ~118.5 MiB; shared-expert fp32 output goes directly to d_out

  init_counts<<<1, 64, 0, stream>>>(counts);
  gate_kernel<<<NTOK / 4, 256, 0, stream>>>(x, gw, gb, topk_idx, topk_w, counts);
  prefix_kernel<<<1, 64, 0, stream>>>(counts, offsets, cursor);
  scatter_kernel<<<NTOK * 4 / 256, 256, 0, stream>>>(topk_idx, cursor, perm, pos);
  convert_all<<<31744, 256, 0, stream>>>(x, Wg, Wu, Wd, Wsg, Wsu, Wsd,
                                         xb, WgB, WuB, WdB, WsgB, WsuB, WsdB);
  // routed gate+up fused -> act[slot][512]
  gemm_bt<true, true, true, unsigned short><<<dim3(512, 4), 256, 0, stream>>>(
      xb, WgB, WuB, act, 0, HID, IMO, (long)IMO * HID, counts, offsets, perm);
  // routed down -> yout[slot][1024]
  gemm_bt<false, false, true, unsigned short><<<dim3(512, 8), 256, 0, stream>>>(
      act, WdB, nullptr, yout, 0, IMO, HID, (long)HID * IMO, counts, offsets, nullptr);
  // shared gate+up fused -> sact[n][1024]
  gemm_bt<true, false, false, unsigned short><<<dim3(32, 8), 256, 0, stream>>>(
      xb, WsgB, WsuB, sact, NTOK, HID, SHI, 0L, nullptr, nullptr, nullptr);
  // shared down -> d_out[n][1024] fp32 (read back by combine before overwrite)
  gemm_bt<false, false, false, float><<<dim3(32, 8), 256, 0, stream>>>(
      sact, WsdB, nullptr, out, NTOK, SHI, HID, 0L, nullptr, nullptr, nullptr);
  // out = x + shared + sum_k w_k * yout[pos]
  combine_kernel<<<NTOK, 256, 0, stream>>>(x, out, yout, topk_w, pos, out);
}

// Round 3
// 470.766 us; speedup vs baseline: 1.7703x; 1.7703x over previous
//
#include <hip/hip_runtime.h>
#include <cstdint>

typedef __bf16 bf16x8 __attribute__((ext_vector_type(8)));
typedef float f32x4 __attribute__((ext_vector_type(4)));
typedef int v4i __attribute__((ext_vector_type(4)));

#define DI __device__ __forceinline__

constexpr int NTOK = 4096;   // B*S
constexpr int HID  = 1024;
constexpr int IMO  = 512;    // moe intermediate
constexpr int NEXP = 16;
constexpr int SHI  = 1024;   // shared intermediate

DI unsigned short f2bf(float f) {
  unsigned u = __float_as_uint(f);
  u = (u + 0x7fffu + ((u >> 16) & 1u)) >> 16;   // round-to-nearest-even
  return (unsigned short)u;
}
DI float bf2f(unsigned short b) { return __uint_as_float(((unsigned)b) << 16); }

// ---------------- init / prefix / scatter ----------------
__global__ void init_counts(int* __restrict__ counts) {
  if (threadIdx.x < NEXP) counts[threadIdx.x] = 0;
}

__global__ void prefix_kernel(const int* __restrict__ counts,
                              int* __restrict__ offsets, int* __restrict__ cursor) {
  if (threadIdx.x == 0 && blockIdx.x == 0) {
    int s = 0;
    for (int e = 0; e < NEXP; ++e) { offsets[e] = s; cursor[e] = s; s += counts[e]; }
    offsets[NEXP] = s;
  }
}

__global__ __launch_bounds__(256) void scatter_kernel(
    const int* __restrict__ topk_idx, int* __restrict__ cursor,
    int* __restrict__ perm, int* __restrict__ pos) {
  int i = blockIdx.x * 256 + threadIdx.x;   // over NTOK*4
  int e = topk_idx[i];
  int slot = atomicAdd(&cursor[e], 1);
  perm[slot] = i >> 2;
  pos[i] = slot;
}

// ---------------- gate (fp64 ranking) ----------------
__global__ __launch_bounds__(256) void gate_kernel(
    const float* __restrict__ x, const float* __restrict__ gw,
    const float* __restrict__ gb, int* __restrict__ topk_idx,
    float* __restrict__ topk_w, int* __restrict__ counts) {
  const int lane = threadIdx.x & 63;
  const int n = blockIdx.x * 4 + (threadIdx.x >> 6);
  const float* xr = x + (size_t)n * HID;
  float xv[16];
#pragma unroll
  for (int j = 0; j < 16; ++j) xv[j] = xr[j * 64 + lane];
  double sig[16], sfc[16];
#pragma unroll
  for (int e = 0; e < 16; ++e) {
    const float* wr = gw + e * HID;
    double acc = 0.0;
#pragma unroll
    for (int j = 0; j < 16; ++j) acc += (double)xv[j] * (double)wr[j * 64 + lane];
#pragma unroll
    for (int m = 32; m >= 1; m >>= 1) acc += __shfl_xor(acc, m, 64);
    double s = 1.0 / (1.0 + exp(-acc));
    sig[e] = s;
    sfc[e] = s + (double)gb[e];
  }
  // group score = sum of top-2 sfc within each group of 4
  double gs[4];
#pragma unroll
  for (int g = 0; g < 4; ++g) {
    double a = sfc[4 * g], b = sfc[4 * g + 1], c = sfc[4 * g + 2], d = sfc[4 * g + 3];
    double mab = fmax(a, b), mcd = fmax(c, d);
    double nab = fmin(a, b), ncd = fmin(c, d);
    gs[g] = fmax(mab, mcd) + fmax(fmax(nab, ncd), fmin(mab, mcd));
  }
  int g1 = 0; double b1 = gs[0];
#pragma unroll
  for (int g = 1; g < 4; ++g) if (gs[g] > b1) { b1 = gs[g]; g1 = g; }
  int g2 = 0; double b2 = -1e300;
#pragma unroll
  for (int g = 0; g < 4; ++g) if (g != g1 && gs[g] > b2) { b2 = gs[g]; g2 = g; }
  unsigned allow = (0xFu << (g1 * 4)) | (0xFu << (g2 * 4));
  unsigned chosen = 0;
  int idx[4]; double wv[4];
#pragma unroll
  for (int k = 0; k < 4; ++k) {
    double bv = -1e300, bw = 0.0; int bi = 0;
#pragma unroll
    for (int t = 0; t < 16; ++t) {
      bool ok = ((allow >> t) & 1u) && !((chosen >> t) & 1u);
      if (ok && sfc[t] > bv) { bv = sfc[t]; bw = sig[t]; bi = t; }
    }
    chosen |= (1u << bi);
    idx[k] = bi; wv[k] = bw;    // weights use sigmoid scores (pre-bias)
  }
  double s = wv[0] + wv[1] + wv[2] + wv[3] + 1e-20;
  if (lane == 0) {
#pragma unroll
    for (int k = 0; k < 4; ++k) {
      topk_idx[n * 4 + k] = idx[k];
      topk_w[n * 4 + k] = (float)(wv[k] / s * 2.5);
      atomicAdd(&counts[idx[k]], 1);
    }
  }
}

// ---------------- fp32 -> bf16 convert (all arrays, one launch) ----------------
__global__ __launch_bounds__(256) void convert_all(
    const float* __restrict__ x, const float* __restrict__ wg,
    const float* __restrict__ wu, const float* __restrict__ wd,
    const float* __restrict__ sg, const float* __restrict__ su,
    const float* __restrict__ sd,
    unsigned short* __restrict__ xb, unsigned short* __restrict__ wgb,
    unsigned short* __restrict__ wub, unsigned short* __restrict__ wdb,
    unsigned short* __restrict__ sgb, unsigned short* __restrict__ sub,
    unsigned short* __restrict__ sdb) {
  long g = (long)blockIdx.x * 256 + threadIdx.x;   // float4 index, total 8126464
  const float* s; unsigned short* d; long o;
  if      (g < 1048576L) { s = x;  d = xb;  o = g; }
  else if (g < 3145728L) { s = wg; d = wgb; o = g - 1048576L; }
  else if (g < 5242880L) { s = wu; d = wub; o = g - 3145728L; }
  else if (g < 7340032L) { s = wd; d = wdb; o = g - 5242880L; }
  else if (g < 7602176L) { s = sg; d = sgb; o = g - 7340032L; }
  else if (g < 7864320L) { s = su; d = sub; o = g - 7602176L; }
  else                   { s = sd; d = sdb; o = g - 7864320L; }
  float4 v = ((const float4*)s)[o];
  ushort4 r;
  r.x = f2bf(v.x); r.y = f2bf(v.y); r.z = f2bf(v.z); r.w = f2bf(v.w);
  ((ushort4*)d)[o] = r;
}

// ---------------- bf16 MFMA GEMM: C = A @ B^T (B stored [out,in]) ----------------
// 128x128 tile, BK=32, 4 waves (2x2), 16x16x32 MFMA, reg-staged double-buffered LDS.
// Staging (round-2 fix): chunk i -> row = i>>2, kc = i&3 so 4 adjacent lanes read
// one contiguous 64B line per row (coalesced); ds_write scatters to [kc][row][8]
// (uniform 8 dwords/bank). Reader layout unchanged (0 bank conflicts measured).
// GU: fused gate+up (two B matrices, silu(g)*u epilogue, bf16 out).
// GATHER: A rows indirected through perm (routed gate/up).
// ROUTED: per-expert blocks with expert->XCD affinity remap.
template <bool GU, bool GATHER, bool ROUTED, typename OutT>
__global__ __launch_bounds__(256) void gemm_bt(
    const unsigned short* __restrict__ A, const unsigned short* __restrict__ B0,
    const unsigned short* __restrict__ B1, void* __restrict__ Cout,
    int M_, int K, int ldc, long eStrideB,
    const int* __restrict__ counts, const int* __restrict__ offsets,
    const int* __restrict__ perm) {
  int e = 0, mt = blockIdx.x, cnt = M_, off = 0;
  if (ROUTED) {
    // XCD affinity: consecutive physical blocks round-robin XCDs; map so each
    // XCD (x&7) owns experts {2c, 2c+1} -> per-XCD L2 holds only 2 experts' B.
    int xp = blockIdx.x;
    e  = ((xp & 7) << 1) | ((xp >> 3) & 1);
    mt = xp >> 4;                       // [0,32)
    cnt = counts[e]; off = offsets[e];
    if (mt * 128 >= cnt) return;
  }
  const int n0 = blockIdx.y * 128;
  const unsigned short* Bg = B0 + (ROUTED ? (long)e * eStrideB : 0L);
  const unsigned short* Bu = GU ? (B1 + (ROUTED ? (long)e * eStrideB : 0L)) : nullptr;

  const int tid = threadIdx.x;
  const int lane = tid & 63;
  const int wid = tid >> 6;
  const int wm = (wid >> 1) * 64, wn = (wid & 1) * 64;

  constexpr int BUFSH = GU ? 12288 : 8192;   // shorts per buffer
  __shared__ __align__(16) unsigned short lds[2 * BUFSH];

  // staging: chunk i = tid + j*256 in [0,512); row = i>>2, kc = i&3.
  // global: 4 lanes x 16B = one 64B line of row's current 32-col K-slice.
  // LDS dest: [kc][row][8] (elem offset (kc*128+row)*8) -- matches reader.
  const unsigned short* aP[2]; const unsigned short* gP[2]; const unsigned short* uP[2];
  int ldsOff[2];
#pragma unroll
  for (int j = 0; j < 2; ++j) {
    int i = tid + j * 256;
    int row = i >> 2, kc = i & 3;
    ldsOff[j] = (kc * 128 + row) * 8;
    int am = mt * 128 + row;
    long ar;
    if (GATHER)      ar = perm[off + (am < cnt ? am : cnt - 1)];
    else if (ROUTED) ar = off + (am < cnt ? am : cnt - 1);
    else             ar = (am < M_ ? am : M_ - 1);
    aP[j] = A + ar * (long)K + kc * 8;
    gP[j] = Bg + (long)(n0 + row) * K + kc * 8;
    if (GU) uP[j] = Bu + (long)(n0 + row) * K + kc * 8;
  }

  f32x4 accg[4][4];
  f32x4 accu[GU ? 4 : 1][GU ? 4 : 1];
#pragma unroll
  for (int a = 0; a < 4; ++a)
#pragma unroll
    for (int b = 0; b < 4; ++b) {
      accg[a][b] = f32x4{0.f, 0.f, 0.f, 0.f};
      if constexpr (GU) accu[a][b] = f32x4{0.f, 0.f, 0.f, 0.f};
    }

  v4i ra[2], rg[2], ru[2];
  auto LOAD = [&]() {
#pragma unroll
    for (int j = 0; j < 2; ++j) {
      ra[j] = *(const v4i*)aP[j]; aP[j] += 32;
      rg[j] = *(const v4i*)gP[j]; gP[j] += 32;
      if constexpr (GU) { ru[j] = *(const v4i*)uP[j]; uP[j] += 32; }
    }
  };
  auto STORE = [&](int buf) {
    unsigned short* d = lds + buf * BUFSH;
#pragma unroll
    for (int j = 0; j < 2; ++j) {
      *(v4i*)(d + ldsOff[j]) = ra[j];
      *(v4i*)(d + 4096 + ldsOff[j]) = rg[j];
      if constexpr (GU) *(v4i*)(d + 8192 + ldsOff[j]) = ru[j];
    }
  };

  const int r16 = lane & 15, kc4 = lane >> 4;
  auto COMPUTE = [&](int buf) {
    const unsigned short* bA = lds + buf * BUFSH;
    const unsigned short* bG = bA + 4096;
    const unsigned short* bU = bA + 8192;
    bf16x8 af[4], gf[4], uf[4];
#pragma unroll
    for (int mi = 0; mi < 4; ++mi)
      af[mi] = *(const bf16x8*)(bA + kc4 * 1024 + (wm + mi * 16 + r16) * 8);
#pragma unroll
    for (int ni = 0; ni < 4; ++ni) {
      gf[ni] = *(const bf16x8*)(bG + kc4 * 1024 + (wn + ni * 16 + r16) * 8);
      if constexpr (GU)
        uf[ni] = *(const bf16x8*)(bU + kc4 * 1024 + (wn + ni * 16 + r16) * 8);
    }
#pragma unroll
    for (int mi = 0; mi < 4; ++mi)
#pragma unroll
      for (int ni = 0; ni < 4; ++ni) {
        accg[mi][ni] = __builtin_amdgcn_mfma_f32_16x16x32_bf16(af[mi], gf[ni], accg[mi][ni], 0, 0, 0);
        if constexpr (GU)
          accu[mi][ni] = __builtin_amdgcn_mfma_f32_16x16x32_bf16(af[mi], uf[ni], accu[mi][ni], 0, 0, 0);
      }
  };

  const int NT = K >> 5;
  LOAD();
  STORE(0);
  __syncthreads();
  int cur = 0;
  for (int t = 0; t < NT; ++t) {
    bool more = (t + 1 < NT);
    if (more) LOAD();          // global loads for t+1 hide under compute
    COMPUTE(cur);
    if (more) STORE(cur ^ 1);
    __syncthreads();
    cur ^= 1;
  }

  // epilogue: C layout col=lane&15, row=(lane>>4)*4+reg  [m89-verified]
#pragma unroll
  for (int mi = 0; mi < 4; ++mi)
#pragma unroll
    for (int ni = 0; ni < 4; ++ni)
#pragma unroll
      for (int j = 0; j < 4; ++j) {
        int r = wm + mi * 16 + kc4 * 4 + j;
        int gr = mt * 128 + r;
        bool okRow = ROUTED ? (gr < cnt) : (gr < M_);
        if (okRow) {
          long crow = (ROUTED ? (long)off : 0L) + gr;
          int c = n0 + wn + ni * 16 + r16;
          if constexpr (GU) {
            float g = accg[mi][ni][j], u = accu[mi][ni][j];
            float sg = g / (1.f + __expf(-g));       // silu
            ((unsigned short*)Cout)[crow * ldc + c] = f2bf(sg * u);
          } else if constexpr (sizeof(OutT) == 2) {
            ((unsigned short*)Cout)[crow * ldc + c] = f2bf(accg[mi][ni][j]);
          } else {
            ((float*)Cout)[crow * ldc + c] = accg[mi][ni][j];
          }
        }
      }
}

// ---------------- final combine: out = x + shared(in d_out) + sum_k w_k*yout ----------------
__global__ __launch_bounds__(256) void combine_kernel(
    const float* __restrict__ x, const float* __restrict__ sh,
    const unsigned short* __restrict__ yout, const float* __restrict__ tw,
    const int* __restrict__ pos, float* __restrict__ out) {
  int n = blockIdx.x;                  // one block per token
  int h4 = threadIdx.x << 2;           // 256 threads * 4 floats = 1024
  float4 xv = *(const float4*)(x + (long)n * HID + h4);
  float4 sv = *(const float4*)(sh + (long)n * HID + h4);   // shared-expert result (read before write)
  float a0 = xv.x + sv.x, a1 = xv.y + sv.y, a2 = xv.z + sv.z, a3 = xv.w + sv.w;
#pragma unroll
  for (int k = 0; k < 4; ++k) {
    float w = tw[n * 4 + k];
    long slot = pos[n * 4 + k];
    ushort4 yv = *(const ushort4*)(yout + slot * HID + h4);
    a0 += w * bf2f(yv.x); a1 += w * bf2f(yv.y);
    a2 += w * bf2f(yv.z); a3 += w * bf2f(yv.w);
  }
  float4 o; o.x = a0; o.y = a1; o.z = a2; o.w = a3;
  *(float4*)(out + (long)n * HID + h4) = o;
}

// ---------------- launch ----------------
extern "C" void kernel_launch(void* const* d_in, const int* in_sizes, int n_in,
                              void* d_out, int out_size, void* d_ws, size_t ws_size,
                              hipStream_t stream) {
  (void)in_sizes; (void)n_in; (void)out_size; (void)ws_size;
  const float* x   = (const float*)d_in[0];
  const float* gw  = (const float*)d_in[1];
  const float* gb  = (const float*)d_in[2];
  const float* Wg  = (const float*)d_in[3];
  const float* Wu  = (const float*)d_in[4];
  const float* Wd  = (const float*)d_in[5];
  const float* Wsg = (const float*)d_in[6];
  const float* Wsu = (const float*)d_in[7];
  const float* Wsd = (const float*)d_in[8];
  float* out = (float*)d_out;

  // ---- workspace layout (big buffers start at 512 KiB; small region ends 262400) ----
  char* w = (char*)d_ws;
  int*   counts   = (int*)(w + 0);                    // 64 B
  int*   cursor   = (int*)(w + 64);                   // 64 B
  int*   offsets  = (int*)(w + 128);                  // 128 B (17 ints)
  int*   topk_idx = (int*)(w + 256);                  // 65536 B
  float* topk_w   = (float*)(w + 256 + 65536);        // 65536 B
  int*   perm     = (int*)(w + 256 + 131072);         // 65536 B
  int*   pos      = (int*)(w + 256 + 196608);         // 65536 B
  size_t o = 524288;                                  // big buffers from 512 KiB
  unsigned short* xb   = (unsigned short*)(w + o); o += (size_t)NTOK * HID * 2;       // 8 MB
  unsigned short* WgB  = (unsigned short*)(w + o); o += (size_t)NEXP * IMO * HID * 2; // 16 MB
  unsigned short* WuB  = (unsigned short*)(w + o); o += (size_t)NEXP * IMO * HID * 2; // 16 MB
  unsigned short* WdB  = (unsigned short*)(w + o); o += (size_t)NEXP * HID * IMO * 2; // 16 MB
  unsigned short* WsgB = (unsigned short*)(w + o); o += (size_t)SHI * HID * 2;        // 2 MB
  unsigned short* WsuB = (unsigned short*)(w + o); o += (size_t)SHI * HID * 2;        // 2 MB
  unsigned short* WsdB = (unsigned short*)(w + o); o += (size_t)HID * SHI * 2;        // 2 MB
  unsigned short* act  = (unsigned short*)(w + o); o += (size_t)NTOK * 4 * IMO * 2;   // 16 MB
  unsigned short* yout = (unsigned short*)(w + o); o += (size_t)NTOK * 4 * HID * 2;   // 32 MB
  unsigned short* sact = (unsigned short*)(w + o); o += (size_t)NTOK * SHI * 2;       // 8 MB
  // total ws use ~118.5 MiB; shared-expert fp32 output goes directly to d_out

  init_counts<<<1, 64, 0, stream>>>(counts);
  gate_kernel<<<NTOK / 4, 256, 0, stream>>>(x, gw, gb, topk_idx, topk_w, counts);
  prefix_kernel<<<1, 64, 0, stream>>>(counts, offsets, cursor);
  scatter_kernel<<<NTOK * 4 / 256, 256, 0, stream>>>(topk_idx, cursor, perm, pos);
  convert_all<<<31744, 256, 0, stream>>>(x, Wg, Wu, Wd, Wsg, Wsu, Wsd,
                                         xb, WgB, WuB, WdB, WsgB, WsuB, WsdB);
  // routed gate+up fused -> act[slot][512]
  gemm_bt<true, true, true, unsigned short><<<dim3(512, 4), 256, 0, stream>>>(
      xb, WgB, WuB, act, 0, HID, IMO, (long)IMO * HID, counts, offsets, perm);
  // routed down -> yout[slot][1024]
  gemm_bt<false, false, true, unsigned short><<<dim3(512, 8), 256, 0, stream>>>(
      act, WdB, nullptr, yout, 0, IMO, HID, (long)HID * IMO, counts, offsets, nullptr);
  // shared gate+up fused -> sact[n][1024]
  gemm_bt<true, false, false, unsigned short><<<dim3(32, 8), 256, 0, stream>>>(
      xb, WsgB, WsuB, sact, NTOK, HID, SHI, 0L, nullptr, nullptr, nullptr);
  // shared down -> d_out[n][1024] fp32 (read back by combine before overwrite)
  gemm_bt<false, false, false, float><<<dim3(32, 8), 256, 0, stream>>>(
      sact, WsdB, nullptr, out, NTOK, SHI, HID, 0L, nullptr, nullptr, nullptr);
  // out = x + shared + sum_k w_k * yout[pos]
  combine_kernel<<<NTOK, 256, 0, stream>>>(x, out, yout, topk_w, pos, out);
}

// Round 4
// 350.141 us; speedup vs baseline: 2.3801x; 1.3445x over previous
//
#include <hip/hip_runtime.h>
#include <cstdint>

typedef __bf16 bf16x8 __attribute__((ext_vector_type(8)));
typedef float f32x4 __attribute__((ext_vector_type(4)));
typedef int v4i __attribute__((ext_vector_type(4)));

#define DI __device__ __forceinline__

constexpr int NTOK = 4096;   // B*S
constexpr int HID  = 1024;
constexpr int IMO  = 512;    // moe intermediate
constexpr int NEXP = 16;
constexpr int SHI  = 1024;   // shared intermediate

DI unsigned short f2bf(float f) {
  unsigned u = __float_as_uint(f);
  u = (u + 0x7fffu + ((u >> 16) & 1u)) >> 16;   // round-to-nearest-even
  return (unsigned short)u;
}
DI float bf2f(unsigned short b) { return __uint_as_float(((unsigned)b) << 16); }

// ---------------- init / prefix / scatter ----------------
__global__ void init_counts(int* __restrict__ counts) {
  if (threadIdx.x < NEXP) counts[threadIdx.x] = 0;
}

__global__ void prefix_kernel(const int* __restrict__ counts,
                              int* __restrict__ offsets, int* __restrict__ cursor) {
  if (threadIdx.x == 0 && blockIdx.x == 0) {
    int s = 0;
    for (int e = 0; e < NEXP; ++e) { offsets[e] = s; cursor[e] = s; s += counts[e]; }
    offsets[NEXP] = s;
  }
}

__global__ __launch_bounds__(256) void scatter_kernel(
    const int* __restrict__ topk_idx, int* __restrict__ cursor,
    int* __restrict__ perm, int* __restrict__ pos) {
  int i = blockIdx.x * 256 + threadIdx.x;   // over NTOK*4
  int e = topk_idx[i];
  int slot = atomicAdd(&cursor[e], 1);
  perm[slot] = i >> 2;
  pos[i] = slot;
}

// ---------------- gate (fp64 ranking, lane-parallel, no per-lane arrays) ----------------
// One wave per token. lane = c*16 + e  (e = expert, c = 256-elem chunk of the dot).
// fp64 dot w/ 8 indep accumulators -> butterfly over chunks (bitwise-symmetric) ->
// sigmoid fp64 -> group top-2 sum (2 shuffle stages) -> group rank (3 shuffles) ->
// expert rank via 15 pipelined shuffle-compares (jax stable-top_k tie-break) ->
// butterfly weight sum. No arrays => no scratch spills (round-3 pathology).
__global__ __launch_bounds__(256) void gate_kernel(
    const float* __restrict__ x, const float* __restrict__ gw,
    const float* __restrict__ gb, int* __restrict__ topk_idx,
    float* __restrict__ topk_w, int* __restrict__ counts) {
  const int lane = threadIdx.x & 63;
  const int n = blockIdx.x * 4 + (threadIdx.x >> 6);
  const int e = lane & 15;          // expert
  const int c = lane >> 4;          // chunk [0,4)
  const int g = e >> 2;             // group [0,4)

  const float4* x4 = (const float4*)(x + (size_t)n * HID + c * 256);
  const float4* w4 = (const float4*)(gw + (size_t)e * HID + c * 256);

  double acc0 = 0, acc1 = 0, acc2 = 0, acc3 = 0, acc4 = 0, acc5 = 0, acc6 = 0, acc7 = 0;
#pragma unroll
  for (int i = 0; i < 32; ++i) {
    float4 xa = x4[2 * i], xb = x4[2 * i + 1];
    float4 wa = w4[2 * i], wb = w4[2 * i + 1];
    acc0 += (double)xa.x * wa.x; acc1 += (double)xa.y * wa.y;
    acc2 += (double)xa.z * wa.z; acc3 += (double)xa.w * wa.w;
    acc4 += (double)xb.x * wb.x; acc5 += (double)xb.y * wb.y;
    acc6 += (double)xb.z * wb.z; acc7 += (double)xb.w * wb.w;
  }
  double L = ((acc0 + acc1) + (acc2 + acc3)) + ((acc4 + acc5) + (acc6 + acc7));
  // reduce over chunks (lane bits 4,5); pairwise-symmetric => bitwise-equal replicas
  L += __shfl_xor(L, 16);
  L += __shfl_xor(L, 32);

  double sig = 1.0 / (1.0 + exp(-L));
  double sfc = sig + (double)gb[e];

  // group score = sum of top-2 sfc within group of 4 (lanes e^1, e^2 are groupmates)
  double o1 = __shfl_xor(sfc, 1);
  double hi = fmax(sfc, o1), lo = fmin(sfc, o1);
  double hi2 = __shfl_xor(hi, 2), lo2 = __shfl_xor(lo, 2);
  double gs = fmax(hi, hi2) + fmax(fmin(hi, hi2), fmax(lo, lo2));

  // rank my group among the 4 group scores (stable: lower index wins ties)
  double gsA = __shfl_xor(gs, 4);    // group g^1
  double gsB = __shfl_xor(gs, 8);    // group g^2
  double gsC = __shfl_xor(gs, 12);   // group g^3
  int grank = 0;
  grank += (gsA > gs || (gsA == gs && (g ^ 1) < g)) ? 1 : 0;
  grank += (gsB > gs || (gsB == gs && (g ^ 2) < g)) ? 1 : 0;
  grank += (gsC > gs || (gsC == gs && (g ^ 3) < g)) ? 1 : 0;
  const bool allowed = grank < 2;

  // expert rank among allowed (masked to -1e300), stable tie-break by index
  double sv = allowed ? sfc : -1e300;
  int rank = 0;
#pragma unroll
  for (int m = 1; m < 16; ++m) {
    double o = __shfl_xor(sv, m);
    int oe = e ^ m;
    rank += (o > sv || (o == sv && oe < e)) ? 1 : 0;
  }
  const bool chosen = allowed && (rank < 4);

  // normalization sum over chosen (butterfly over 16 lanes; bitwise-symmetric)
  double t = chosen ? sig : 0.0;
  t += __shfl_xor(t, 1);
  t += __shfl_xor(t, 2);
  t += __shfl_xor(t, 4);
  t += __shfl_xor(t, 8);

  if (chosen && c == 0) {
    topk_idx[n * 4 + rank] = e;
    topk_w[n * 4 + rank] = (float)(sig / (t + 1e-20) * 2.5);
    atomicAdd(&counts[e], 1);
  }
}

// ---------------- fp32 -> bf16 convert (all arrays, one launch) ----------------
__global__ __launch_bounds__(256) void convert_all(
    const float* __restrict__ x, const float* __restrict__ wg,
    const float* __restrict__ wu, const float* __restrict__ wd,
    const float* __restrict__ sg, const float* __restrict__ su,
    const float* __restrict__ sd,
    unsigned short* __restrict__ xb, unsigned short* __restrict__ wgb,
    unsigned short* __restrict__ wub, unsigned short* __restrict__ wdb,
    unsigned short* __restrict__ sgb, unsigned short* __restrict__ sub,
    unsigned short* __restrict__ sdb) {
  long g = (long)blockIdx.x * 256 + threadIdx.x;   // float4 index, total 8126464
  const float* s; unsigned short* d; long o;
  if      (g < 1048576L) { s = x;  d = xb;  o = g; }
  else if (g < 3145728L) { s = wg; d = wgb; o = g - 1048576L; }
  else if (g < 5242880L) { s = wu; d = wub; o = g - 3145728L; }
  else if (g < 7340032L) { s = wd; d = wdb; o = g - 5242880L; }
  else if (g < 7602176L) { s = sg; d = sgb; o = g - 7340032L; }
  else if (g < 7864320L) { s = su; d = sub; o = g - 7602176L; }
  else                   { s = sd; d = sdb; o = g - 7864320L; }
  float4 v = ((const float4*)s)[o];
  ushort4 r;
  r.x = f2bf(v.x); r.y = f2bf(v.y); r.z = f2bf(v.z); r.w = f2bf(v.w);
  ((ushort4*)d)[o] = r;
}

// ---------------- bf16 MFMA GEMM: C = A @ B^T (B stored [out,in]) ----------------
// 128x128 tile, BK=32, 4 waves (2x2), 16x16x32 MFMA, reg-staged double-buffered LDS.
// Staging: chunk i -> row = i>>2, kc = i&3 so 4 adjacent lanes read one contiguous
// 64B line per row (coalesced); ds_write scatters to [kc][row][8].
// GU: fused gate+up (two B matrices, silu(g)*u epilogue, bf16 out).
// GATHER: A rows indirected through perm (routed gate/up).
// ROUTED: per-expert blocks with expert->XCD affinity remap.
template <bool GU, bool GATHER, bool ROUTED, typename OutT>
__global__ __launch_bounds__(256) void gemm_bt(
    const unsigned short* __restrict__ A, const unsigned short* __restrict__ B0,
    const unsigned short* __restrict__ B1, void* __restrict__ Cout,
    int M_, int K, int ldc, long eStrideB,
    const int* __restrict__ counts, const int* __restrict__ offsets,
    const int* __restrict__ perm) {
  int e = 0, mt = blockIdx.x, cnt = M_, off = 0;
  if (ROUTED) {
    // XCD affinity: consecutive physical blocks round-robin XCDs; map so each
    // XCD (x&7) owns experts {2c, 2c+1} -> per-XCD L2 holds only 2 experts' B.
    int xp = blockIdx.x;
    e  = ((xp & 7) << 1) | ((xp >> 3) & 1);
    mt = xp >> 4;                       // [0,32)
    cnt = counts[e]; off = offsets[e];
    if (mt * 128 >= cnt) return;
  }
  const int n0 = blockIdx.y * 128;
  const unsigned short* Bg = B0 + (ROUTED ? (long)e * eStrideB : 0L);
  const unsigned short* Bu = GU ? (B1 + (ROUTED ? (long)e * eStrideB : 0L)) : nullptr;

  const int tid = threadIdx.x;
  const int lane = tid & 63;
  const int wid = tid >> 6;
  const int wm = (wid >> 1) * 64, wn = (wid & 1) * 64;

  constexpr int BUFSH = GU ? 12288 : 8192;   // shorts per buffer
  __shared__ __align__(16) unsigned short lds[2 * BUFSH];

  // staging: chunk i = tid + j*256 in [0,512); row = i>>2, kc = i&3.
  // global: 4 lanes x 16B = one 64B line of row's current 32-col K-slice.
  // LDS dest: [kc][row][8] (elem offset (kc*128+row)*8) -- matches reader.
  const unsigned short* aP[2]; const unsigned short* gP[2]; const unsigned short* uP[2];
  int ldsOff[2];
#pragma unroll
  for (int j = 0; j < 2; ++j) {
    int i = tid + j * 256;
    int row = i >> 2, kc = i & 3;
    ldsOff[j] = (kc * 128 + row) * 8;
    int am = mt * 128 + row;
    long ar;
    if (GATHER)      ar = perm[off + (am < cnt ? am : cnt - 1)];
    else if (ROUTED) ar = off + (am < cnt ? am : cnt - 1);
    else             ar = (am < M_ ? am : M_ - 1);
    aP[j] = A + ar * (long)K + kc * 8;
    gP[j] = Bg + (long)(n0 + row) * K + kc * 8;
    if (GU) uP[j] = Bu + (long)(n0 + row) * K + kc * 8;
  }

  f32x4 accg[4][4];
  f32x4 accu[GU ? 4 : 1][GU ? 4 : 1];
#pragma unroll
  for (int a = 0; a < 4; ++a)
#pragma unroll
    for (int b = 0; b < 4; ++b) {
      accg[a][b] = f32x4{0.f, 0.f, 0.f, 0.f};
      if constexpr (GU) accu[a][b] = f32x4{0.f, 0.f, 0.f, 0.f};
    }

  v4i ra[2], rg[2], ru[2];
  auto LOAD = [&]() {
#pragma unroll
    for (int j = 0; j < 2; ++j) {
      ra[j] = *(const v4i*)aP[j]; aP[j] += 32;
      rg[j] = *(const v4i*)gP[j]; gP[j] += 32;
      if constexpr (GU) { ru[j] = *(const v4i*)uP[j]; uP[j] += 32; }
    }
  };
  auto STORE = [&](int buf) {
    unsigned short* d = lds + buf * BUFSH;
#pragma unroll
    for (int j = 0; j < 2; ++j) {
      *(v4i*)(d + ldsOff[j]) = ra[j];
      *(v4i*)(d + 4096 + ldsOff[j]) = rg[j];
      if constexpr (GU) *(v4i*)(d + 8192 + ldsOff[j]) = ru[j];
    }
  };

  const int r16 = lane & 15, kc4 = lane >> 4;
  auto COMPUTE = [&](int buf) {
    const unsigned short* bA = lds + buf * BUFSH;
    const unsigned short* bG = bA + 4096;
    const unsigned short* bU = bA + 8192;
    bf16x8 af[4], gf[4], uf[4];
#pragma unroll
    for (int mi = 0; mi < 4; ++mi)
      af[mi] = *(const bf16x8*)(bA + kc4 * 1024 + (wm + mi * 16 + r16) * 8);
#pragma unroll
    for (int ni = 0; ni < 4; ++ni) {
      gf[ni] = *(const bf16x8*)(bG + kc4 * 1024 + (wn + ni * 16 + r16) * 8);
      if constexpr (GU)
        uf[ni] = *(const bf16x8*)(bU + kc4 * 1024 + (wn + ni * 16 + r16) * 8);
    }
#pragma unroll
    for (int mi = 0; mi < 4; ++mi)
#pragma unroll
      for (int ni = 0; ni < 4; ++ni) {
        accg[mi][ni] = __builtin_amdgcn_mfma_f32_16x16x32_bf16(af[mi], gf[ni], accg[mi][ni], 0, 0, 0);
        if constexpr (GU)
          accu[mi][ni] = __builtin_amdgcn_mfma_f32_16x16x32_bf16(af[mi], uf[ni], accu[mi][ni], 0, 0, 0);
      }
  };

  const int NT = K >> 5;
  LOAD();
  STORE(0);
  __syncthreads();
  int cur = 0;
  for (int t = 0; t < NT; ++t) {
    bool more = (t + 1 < NT);
    if (more) LOAD();          // global loads for t+1 hide under compute
    COMPUTE(cur);
    if (more) STORE(cur ^ 1);
    __syncthreads();
    cur ^= 1;
  }

  // epilogue: C layout col=lane&15, row=(lane>>4)*4+reg  [m89-verified]
#pragma unroll
  for (int mi = 0; mi < 4; ++mi)
#pragma unroll
    for (int ni = 0; ni < 4; ++ni)
#pragma unroll
      for (int j = 0; j < 4; ++j) {
        int r = wm + mi * 16 + kc4 * 4 + j;
        int gr = mt * 128 + r;
        bool okRow = ROUTED ? (gr < cnt) : (gr < M_);
        if (okRow) {
          long crow = (ROUTED ? (long)off : 0L) + gr;
          int c = n0 + wn + ni * 16 + r16;
          if constexpr (GU) {
            float g = accg[mi][ni][j], u = accu[mi][ni][j];
            float sg = g / (1.f + __expf(-g));       // silu
            ((unsigned short*)Cout)[crow * ldc + c] = f2bf(sg * u);
          } else if constexpr (sizeof(OutT) == 2) {
            ((unsigned short*)Cout)[crow * ldc + c] = f2bf(accg[mi][ni][j]);
          } else {
            ((float*)Cout)[crow * ldc + c] = accg[mi][ni][j];
          }
        }
      }
}

// ---------------- final combine: out = x + shared(in d_out) + sum_k w_k*yout ----------------
__global__ __launch_bounds__(256) void combine_kernel(
    const float* __restrict__ x, const float* __restrict__ sh,
    const unsigned short* __restrict__ yout, const float* __restrict__ tw,
    const int* __restrict__ pos, float* __restrict__ out) {
  int n = blockIdx.x;                  // one block per token
  int h4 = threadIdx.x << 2;           // 256 threads * 4 floats = 1024
  float4 xv = *(const float4*)(x + (long)n * HID + h4);
  float4 sv = *(const float4*)(sh + (long)n * HID + h4);   // shared-expert result (read before write)
  float a0 = xv.x + sv.x, a1 = xv.y + sv.y, a2 = xv.z + sv.z, a3 = xv.w + sv.w;
#pragma unroll
  for (int k = 0; k < 4; ++k) {
    float w = tw[n * 4 + k];
    long slot = pos[n * 4 + k];
    ushort4 yv = *(const ushort4*)(yout + slot * HID + h4);
    a0 += w * bf2f(yv.x); a1 += w * bf2f(yv.y);
    a2 += w * bf2f(yv.z); a3 += w * bf2f(yv.w);
  }
  float4 o; o.x = a0; o.y = a1; o.z = a2; o.w = a3;
  *(float4*)(out + (long)n * HID + h4) = o;
}

// ---------------- launch ----------------
extern "C" void kernel_launch(void* const* d_in, const int* in_sizes, int n_in,
                              void* d_out, int out_size, void* d_ws, size_t ws_size,
                              hipStream_t stream) {
  (void)in_sizes; (void)n_in; (void)out_size; (void)ws_size;
  const float* x   = (const float*)d_in[0];
  const float* gw  = (const float*)d_in[1];
  const float* gb  = (const float*)d_in[2];
  const float* Wg  = (const float*)d_in[3];
  const float* Wu  = (const float*)d_in[4];
  const float* Wd  = (const float*)d_in[5];
  const float* Wsg = (const float*)d_in[6];
  const float* Wsu = (const float*)d_in[7];
  const float* Wsd = (const float*)d_in[8];
  float* out = (float*)d_out;

  // ---- workspace layout (big buffers start at 512 KiB; small region ends 262400) ----
  char* w = (char*)d_ws;
  int*   counts   = (int*)(w + 0);                    // 64 B
  int*   cursor   = (int*)(w + 64);                   // 64 B
  int*   offsets  = (int*)(w + 128);                  // 128 B (17 ints)
  int*   topk_idx = (int*)(w + 256);                  // 65536 B
  float* topk_w   = (float*)(w + 256 + 65536);        // 65536 B
  int*   perm     = (int*)(w + 256 + 131072);         // 65536 B
  int*   pos      = (int*)(w + 256 + 196608);         // 65536 B
  size_t o = 524288;                                  // big buffers from 512 KiB
  unsigned short* xb   = (unsigned short*)(w + o); o += (size_t)NTOK * HID * 2;       // 8 MB
  unsigned short* WgB  = (unsigned short*)(w + o); o += (size_t)NEXP * IMO * HID * 2; // 16 MB
  unsigned short* WuB  = (unsigned short*)(w + o); o += (size_t)NEXP * IMO * HID * 2; // 16 MB
  unsigned short* WdB  = (unsigned short*)(w + o); o += (size_t)NEXP * HID * IMO * 2; // 16 MB
  unsigned short* WsgB = (unsigned short*)(w + o); o += (size_t)SHI * HID * 2;        // 2 MB
  unsigned short* WsuB = (unsigned short*)(w + o); o += (size_t)SHI * HID * 2;        // 2 MB
  unsigned short* WsdB = (unsigned short*)(w + o); o += (size_t)HID * SHI * 2;        // 2 MB
  unsigned short* act  = (unsigned short*)(w + o); o += (size_t)NTOK * 4 * IMO * 2;   // 16 MB
  unsigned short* yout = (unsigned short*)(w + o); o += (size_t)NTOK * 4 * HID * 2;   // 32 MB
  unsigned short* sact = (unsigned short*)(w + o); o += (size_t)NTOK * SHI * 2;       // 8 MB
  // total ws use ~118.5 MiB; shared-expert fp32 output goes directly to d_out

  init_counts<<<1, 64, 0, stream>>>(counts);
  gate_kernel<<<NTOK / 4, 256, 0, stream>>>(x, gw, gb, topk_idx, topk_w, counts);
  prefix_kernel<<<1, 64, 0, stream>>>(counts, offsets, cursor);
  scatter_kernel<<<NTOK * 4 / 256, 256, 0, stream>>>(topk_idx, cursor, perm, pos);
  convert_all<<<31744, 256, 0, stream>>>(x, Wg, Wu, Wd, Wsg, Wsu, Wsd,
                                         xb, WgB, WuB, WdB, WsgB, WsuB, WsdB);
  // routed gate+up fused -> act[slot][512]
  gemm_bt<true, true, true, unsigned short><<<dim3(512, 4), 256, 0, stream>>>(
      xb, WgB, WuB, act, 0, HID, IMO, (long)IMO * HID, counts, offsets, perm);
  // routed down -> yout[slot][1024]
  gemm_bt<false, false, true, unsigned short><<<dim3(512, 8), 256, 0, stream>>>(
      act, WdB, nullptr, yout, 0, IMO, HID, (long)HID * IMO, counts, offsets, nullptr);
  // shared gate+up fused -> sact[n][1024]
  gemm_bt<true, false, false, unsigned short><<<dim3(32, 8), 256, 0, stream>>>(
      xb, WsgB, WsuB, sact, NTOK, HID, SHI, 0L, nullptr, nullptr, nullptr);
  // shared down -> d_out[n][1024] fp32 (read back by combine before overwrite)
  gemm_bt<false, false, false, float><<<dim3(32, 8), 256, 0, stream>>>(
      sact, WsdB, nullptr, out, NTOK, SHI, HID, 0L, nullptr, nullptr, nullptr);
  // out = x + shared + sum_k w_k * yout[pos]
  combine_kernel<<<NTOK, 256, 0, stream>>>(x, out, yout, topk_w, pos, out);
}

// Round 5
// 338.625 us; speedup vs baseline: 2.4611x; 1.0340x over previous
//
#include <hip/hip_runtime.h>
#include <cstdint>

typedef __bf16 bf16x8 __attribute__((ext_vector_type(8)));
typedef float f32x4 __attribute__((ext_vector_type(4)));

#define DI __device__ __forceinline__

constexpr int NTOK = 4096;   // B*S
constexpr int HID  = 1024;
constexpr int IMO  = 512;    // moe intermediate
constexpr int NEXP = 16;
constexpr int SHI  = 1024;   // shared intermediate

// async global->LDS, 16B per lane, wave-uniform LDS base (m97/m193 pattern)
#define GLOAD_LDS(g, l) __builtin_amdgcn_global_load_lds( \
    (const __attribute__((address_space(1))) unsigned int*)(const void*)(g), \
    (__attribute__((address_space(3))) unsigned int*)(void*)(l), 16, 0, 0)

DI unsigned short f2bf(float f) {
  unsigned u = __float_as_uint(f);
  u = (u + 0x7fffu + ((u >> 16) & 1u)) >> 16;   // round-to-nearest-even
  return (unsigned short)u;
}
DI float bf2f(unsigned short b) { return __uint_as_float(((unsigned)b) << 16); }

// ---------------- init / prefix / scatter ----------------
__global__ void init_counts(int* __restrict__ counts) {
  if (threadIdx.x < NEXP) counts[threadIdx.x] = 0;
}

__global__ void prefix_kernel(const int* __restrict__ counts,
                              int* __restrict__ offsets, int* __restrict__ cursor) {
  if (threadIdx.x == 0 && blockIdx.x == 0) {
    int s = 0;
    for (int e = 0; e < NEXP; ++e) { offsets[e] = s; cursor[e] = s; s += counts[e]; }
    offsets[NEXP] = s;
  }
}

__global__ __launch_bounds__(256) void scatter_kernel(
    const int* __restrict__ topk_idx, int* __restrict__ cursor,
    int* __restrict__ perm, int* __restrict__ pos) {
  int i = blockIdx.x * 256 + threadIdx.x;   // over NTOK*4
  int e = topk_idx[i];
  int slot = atomicAdd(&cursor[e], 1);
  perm[slot] = i >> 2;
  pos[i] = slot;
}

// ---------------- gate (fp64 ranking, lane-parallel, no per-lane arrays) ----------------
__global__ __launch_bounds__(256) void gate_kernel(
    const float* __restrict__ x, const float* __restrict__ gw,
    const float* __restrict__ gb, int* __restrict__ topk_idx,
    float* __restrict__ topk_w, int* __restrict__ counts) {
  const int lane = threadIdx.x & 63;
  const int n = blockIdx.x * 4 + (threadIdx.x >> 6);
  const int e = lane & 15;          // expert
  const int c = lane >> 4;          // chunk [0,4)
  const int g = e >> 2;             // group [0,4)

  const float4* x4 = (const float4*)(x + (size_t)n * HID + c * 256);
  const float4* w4 = (const float4*)(gw + (size_t)e * HID + c * 256);

  double acc0 = 0, acc1 = 0, acc2 = 0, acc3 = 0, acc4 = 0, acc5 = 0, acc6 = 0, acc7 = 0;
#pragma unroll
  for (int i = 0; i < 32; ++i) {
    float4 xa = x4[2 * i], xb = x4[2 * i + 1];
    float4 wa = w4[2 * i], wb = w4[2 * i + 1];
    acc0 += (double)xa.x * wa.x; acc1 += (double)xa.y * wa.y;
    acc2 += (double)xa.z * wa.z; acc3 += (double)xa.w * wa.w;
    acc4 += (double)xb.x * wb.x; acc5 += (double)xb.y * wb.y;
    acc6 += (double)xb.z * wb.z; acc7 += (double)xb.w * wb.w;
  }
  double L = ((acc0 + acc1) + (acc2 + acc3)) + ((acc4 + acc5) + (acc6 + acc7));
  L += __shfl_xor(L, 16);
  L += __shfl_xor(L, 32);

  double sig = 1.0 / (1.0 + exp(-L));
  double sfc = sig + (double)gb[e];

  // group score = sum of top-2 sfc within group of 4
  double o1 = __shfl_xor(sfc, 1);
  double hi = fmax(sfc, o1), lo = fmin(sfc, o1);
  double hi2 = __shfl_xor(hi, 2), lo2 = __shfl_xor(lo, 2);
  double gs = fmax(hi, hi2) + fmax(fmin(hi, hi2), fmax(lo, lo2));

  // rank my group among the 4 group scores (stable)
  double gsA = __shfl_xor(gs, 4);
  double gsB = __shfl_xor(gs, 8);
  double gsC = __shfl_xor(gs, 12);
  int grank = 0;
  grank += (gsA > gs || (gsA == gs && (g ^ 1) < g)) ? 1 : 0;
  grank += (gsB > gs || (gsB == gs && (g ^ 2) < g)) ? 1 : 0;
  grank += (gsC > gs || (gsC == gs && (g ^ 3) < g)) ? 1 : 0;
  const bool allowed = grank < 2;

  // expert rank among allowed, stable tie-break by index
  double sv = allowed ? sfc : -1e300;
  int rank = 0;
#pragma unroll
  for (int m = 1; m < 16; ++m) {
    double o = __shfl_xor(sv, m);
    int oe = e ^ m;
    rank += (o > sv || (o == sv && oe < e)) ? 1 : 0;
  }
  const bool chosen = allowed && (rank < 4);

  double t = chosen ? sig : 0.0;
  t += __shfl_xor(t, 1);
  t += __shfl_xor(t, 2);
  t += __shfl_xor(t, 4);
  t += __shfl_xor(t, 8);

  if (chosen && c == 0) {
    topk_idx[n * 4 + rank] = e;
    topk_w[n * 4 + rank] = (float)(sig / (t + 1e-20) * 2.5);
    atomicAdd(&counts[e], 1);
  }
}

// ---------------- fp32 -> bf16 convert (all arrays, one launch) ----------------
__global__ __launch_bounds__(256) void convert_all(
    const float* __restrict__ x, const float* __restrict__ wg,
    const float* __restrict__ wu, const float* __restrict__ wd,
    const float* __restrict__ sg, const float* __restrict__ su,
    const float* __restrict__ sd,
    unsigned short* __restrict__ xb, unsigned short* __restrict__ wgb,
    unsigned short* __restrict__ wub, unsigned short* __restrict__ wdb,
    unsigned short* __restrict__ sgb, unsigned short* __restrict__ sub,
    unsigned short* __restrict__ sdb) {
  long g = (long)blockIdx.x * 256 + threadIdx.x;   // float4 index, total 8126464
  const float* s; unsigned short* d; long o;
  if      (g < 1048576L) { s = x;  d = xb;  o = g; }
  else if (g < 3145728L) { s = wg; d = wgb; o = g - 1048576L; }
  else if (g < 5242880L) { s = wu; d = wub; o = g - 3145728L; }
  else if (g < 7340032L) { s = wd; d = wdb; o = g - 5242880L; }
  else if (g < 7602176L) { s = sg; d = sgb; o = g - 7340032L; }
  else if (g < 7864320L) { s = su; d = sub; o = g - 7602176L; }
  else                   { s = sd; d = sdb; o = g - 7864320L; }
  float4 v = ((const float4*)s)[o];
  ushort4 r;
  r.x = f2bf(v.x); r.y = f2bf(v.y); r.z = f2bf(v.z); r.w = f2bf(v.w);
  ((ushort4*)d)[o] = r;
}

// ---------------- bf16 MFMA GEMM: C = A @ B^T (B stored [out,in]) ----------------
// 128x128 tile, BK=32, 4 waves (2x2), 16x16x32 MFMA.
// Staging via global_load_lds (width=16): LDS layout [row 128][32 shorts] per array;
// chunk c = row*4 + kc matches lane order, so the wave-uniform-base DMA writes it
// directly (no ds_write -> no write bank conflicts; round-4 had 9.8M).
// Reads row*64B + kc4*16B: even rows banks 0-15, odd rows 16-31, 8 dwords/bank
// uniform = conflict-free. Loop = m97 2-phase: STAGE(next); COMPUTE(cur); barrier.
template <bool GU, bool GATHER, bool ROUTED, typename OutT>
__global__ __launch_bounds__(256) void gemm_bt(
    const unsigned short* __restrict__ A, const unsigned short* __restrict__ B0,
    const unsigned short* __restrict__ B1, void* __restrict__ Cout,
    int M_, int K, int ldc, long eStrideB,
    const int* __restrict__ counts, const int* __restrict__ offsets,
    const int* __restrict__ perm) {
  int e = 0, mt = blockIdx.x, cnt = M_, off = 0;
  if (ROUTED) {
    // XCD affinity: XCD (x&7) owns experts {2c, 2c+1}
    int xp = blockIdx.x;
    e  = ((xp & 7) << 1) | ((xp >> 3) & 1);
    mt = xp >> 4;                       // [0,32)
    cnt = counts[e]; off = offsets[e];
    if (mt * 128 >= cnt) return;
  }
  const int n0 = blockIdx.y * 128;
  const unsigned short* Bg = B0 + (ROUTED ? (long)e * eStrideB : 0L);
  const unsigned short* Bu = GU ? (B1 + (ROUTED ? (long)e * eStrideB : 0L)) : nullptr;

  const int tid = threadIdx.x;
  const int lane = tid & 63;
  const int wid = tid >> 6;
  const int wm = (wid >> 1) * 64, wn = (wid & 1) * 64;

  constexpr int ABYTES = 8192;                 // one array's 128x32-short tile
  constexpr int BUFB = GU ? 24576 : 16384;     // buffer stride (bytes)
  __shared__ __align__(16) unsigned char lds[2 * (GU ? 24576 : 16384)];

  // staging geometry: instr j covers chunks c in [(wid*2+j)*64, +64);
  // lane l: c = c0 + l, row = c>>2, kc = c&3  (16 rows x 64B contiguous per instr)
  const unsigned short* aP[2]; const unsigned short* gP[2]; const unsigned short* uP[2];
  int ldsC0[2];
#pragma unroll
  for (int j = 0; j < 2; ++j) {
    int c = (wid * 2 + j) * 64 + lane;
    int row = c >> 2, kc = c & 3;
    ldsC0[j] = (wid * 2 + j) * 1024;           // byte offset of this instr's 1KB dest
    int am = mt * 128 + row;
    long ar;
    if (GATHER)      ar = perm[off + (am < cnt ? am : cnt - 1)];
    else if (ROUTED) ar = off + (am < cnt ? am : cnt - 1);
    else             ar = (am < M_ ? am : M_ - 1);
    aP[j] = A + ar * (long)K + kc * 8;
    gP[j] = Bg + (long)(n0 + row) * K + kc * 8;
    if (GU) uP[j] = Bu + (long)(n0 + row) * K + kc * 8;
  }

  auto STAGE = [&](int buf, int t) {
    unsigned char* base = lds + buf * BUFB;
    const int koff = t * 32;                   // shorts
#pragma unroll
    for (int j = 0; j < 2; ++j) {
      GLOAD_LDS(aP[j] + koff, base + ldsC0[j]);
      GLOAD_LDS(gP[j] + koff, base + ABYTES + ldsC0[j]);
      if constexpr (GU) GLOAD_LDS(uP[j] + koff, base + 2 * ABYTES + ldsC0[j]);
    }
  };

  f32x4 accg[4][4];
  f32x4 accu[GU ? 4 : 1][GU ? 4 : 1];
#pragma unroll
  for (int a = 0; a < 4; ++a)
#pragma unroll
    for (int b = 0; b < 4; ++b) {
      accg[a][b] = f32x4{0.f, 0.f, 0.f, 0.f};
      if constexpr (GU) accu[a][b] = f32x4{0.f, 0.f, 0.f, 0.f};
    }

  const int r16 = lane & 15, kc4 = lane >> 4;
  auto COMPUTE = [&](int buf) {
    const unsigned short* bA = (const unsigned short*)(lds + buf * BUFB);
    const unsigned short* bG = bA + 4096;      // +8192 B
    const unsigned short* bU = bA + 8192;      // +16384 B
    bf16x8 af[4], gf[4], uf[4];
#pragma unroll
    for (int mi = 0; mi < 4; ++mi)
      af[mi] = *(const bf16x8*)(bA + (wm + mi * 16 + r16) * 32 + kc4 * 8);
#pragma unroll
    for (int ni = 0; ni < 4; ++ni) {
      gf[ni] = *(const bf16x8*)(bG + (wn + ni * 16 + r16) * 32 + kc4 * 8);
      if constexpr (GU)
        uf[ni] = *(const bf16x8*)(bU + (wn + ni * 16 + r16) * 32 + kc4 * 8);
    }
#pragma unroll
    for (int mi = 0; mi < 4; ++mi)
#pragma unroll
      for (int ni = 0; ni < 4; ++ni) {
        accg[mi][ni] = __builtin_amdgcn_mfma_f32_16x16x32_bf16(af[mi], gf[ni], accg[mi][ni], 0, 0, 0);
        if constexpr (GU)
          accu[mi][ni] = __builtin_amdgcn_mfma_f32_16x16x32_bf16(af[mi], uf[ni], accu[mi][ni], 0, 0, 0);
      }
  };

  const int NT = K >> 5;
  STAGE(0, 0);
  __syncthreads();                 // drains vmcnt -> buf0 ready
  int cur = 0;
  for (int t = 0; t < NT; ++t) {
    if (t + 1 < NT) STAGE(cur ^ 1, t + 1);   // prefetch in flight under compute
    COMPUTE(cur);
    __syncthreads();               // vmcnt(0) drain + barrier -> next buf ready
    cur ^= 1;
  }

  // epilogue: C layout col=lane&15, row=(lane>>4)*4+reg  [m89-verified]
#pragma unroll
  for (int mi = 0; mi < 4; ++mi)
#pragma unroll
    for (int ni = 0; ni < 4; ++ni)
#pragma unroll
      for (int j = 0; j < 4; ++j) {
        int r = wm + mi * 16 + kc4 * 4 + j;
        int gr = mt * 128 + r;
        bool okRow = ROUTED ? (gr < cnt) : (gr < M_);
        if (okRow) {
          long crow = (ROUTED ? (long)off : 0L) + gr;
          int c = n0 + wn + ni * 16 + r16;
          if constexpr (GU) {
            float g = accg[mi][ni][j], u = accu[mi][ni][j];
            float sg = g / (1.f + __expf(-g));       // silu
            ((unsigned short*)Cout)[crow * ldc + c] = f2bf(sg * u);
          } else if constexpr (sizeof(OutT) == 2) {
            ((unsigned short*)Cout)[crow * ldc + c] = f2bf(accg[mi][ni][j]);
          } else {
            ((float*)Cout)[crow * ldc + c] = accg[mi][ni][j];
          }
        }
      }
}

// ---------------- final combine: out = x + shared(in d_out) + sum_k w_k*yout ----------------
__global__ __launch_bounds__(256) void combine_kernel(
    const float* __restrict__ x, const float* __restrict__ sh,
    const unsigned short* __restrict__ yout, const float* __restrict__ tw,
    const int* __restrict__ pos, float* __restrict__ out) {
  int n = blockIdx.x;                  // one block per token
  int h4 = threadIdx.x << 2;           // 256 threads * 4 floats = 1024
  float4 xv = *(const float4*)(x + (long)n * HID + h4);
  float4 sv = *(const float4*)(sh + (long)n * HID + h4);   // shared-expert result (read before write)
  float a0 = xv.x + sv.x, a1 = xv.y + sv.y, a2 = xv.z + sv.z, a3 = xv.w + sv.w;
#pragma unroll
  for (int k = 0; k < 4; ++k) {
    float w = tw[n * 4 + k];
    long slot = pos[n * 4 + k];
    ushort4 yv = *(const ushort4*)(yout + slot * HID + h4);
    a0 += w * bf2f(yv.x); a1 += w * bf2f(yv.y);
    a2 += w * bf2f(yv.z); a3 += w * bf2f(yv.w);
  }
  float4 o; o.x = a0; o.y = a1; o.z = a2; o.w = a3;
  *(float4*)(out + (long)n * HID + h4) = o;
}

// ---------------- launch ----------------
extern "C" void kernel_launch(void* const* d_in, const int* in_sizes, int n_in,
                              void* d_out, int out_size, void* d_ws, size_t ws_size,
                              hipStream_t stream) {
  (void)in_sizes; (void)n_in; (void)out_size; (void)ws_size;
  const float* x   = (const float*)d_in[0];
  const float* gw  = (const float*)d_in[1];
  const float* gb  = (const float*)d_in[2];
  const float* Wg  = (const float*)d_in[3];
  const float* Wu  = (const float*)d_in[4];
  const float* Wd  = (const float*)d_in[5];
  const float* Wsg = (const float*)d_in[6];
  const float* Wsu = (const float*)d_in[7];
  const float* Wsd = (const float*)d_in[8];
  float* out = (float*)d_out;

  // ---- workspace layout (big buffers start at 512 KiB; small region ends 262400) ----
  char* w = (char*)d_ws;
  int*   counts   = (int*)(w + 0);                    // 64 B
  int*   cursor   = (int*)(w + 64);                   // 64 B
  int*   offsets  = (int*)(w + 128);                  // 128 B (17 ints)
  int*   topk_idx = (int*)(w + 256);                  // 65536 B
  float* topk_w   = (float*)(w + 256 + 65536);        // 65536 B
  int*   perm     = (int*)(w + 256 + 131072);         // 65536 B
  int*   pos      = (int*)(w + 256 + 196608);         // 65536 B
  size_t o = 524288;                                  // big buffers from 512 KiB
  unsigned short* xb   = (unsigned short*)(w + o); o += (size_t)NTOK * HID * 2;       // 8 MB
  unsigned short* WgB  = (unsigned short*)(w + o); o += (size_t)NEXP * IMO * HID * 2; // 16 MB
  unsigned short* WuB  = (unsigned short*)(w + o); o += (size_t)NEXP * IMO * HID * 2; // 16 MB
  unsigned short* WdB  = (unsigned short*)(w + o); o += (size_t)NEXP * HID * IMO * 2; // 16 MB
  unsigned short* WsgB = (unsigned short*)(w + o); o += (size_t)SHI * HID * 2;        // 2 MB
  unsigned short* WsuB = (unsigned short*)(w + o); o += (size_t)SHI * HID * 2;        // 2 MB
  unsigned short* WsdB = (unsigned short*)(w + o); o += (size_t)HID * SHI * 2;        // 2 MB
  unsigned short* act  = (unsigned short*)(w + o); o += (size_t)NTOK * 4 * IMO * 2;   // 16 MB
  unsigned short* yout = (unsigned short*)(w + o); o += (size_t)NTOK * 4 * HID * 2;   // 32 MB
  unsigned short* sact = (unsigned short*)(w + o); o += (size_t)NTOK * SHI * 2;       // 8 MB
  // total ws use ~118.5 MiB; shared-expert fp32 output goes directly to d_out

  init_counts<<<1, 64, 0, stream>>>(counts);
  gate_kernel<<<NTOK / 4, 256, 0, stream>>>(x, gw, gb, topk_idx, topk_w, counts);
  prefix_kernel<<<1, 64, 0, stream>>>(counts, offsets, cursor);
  scatter_kernel<<<NTOK * 4 / 256, 256, 0, stream>>>(topk_idx, cursor, perm, pos);
  convert_all<<<31744, 256, 0, stream>>>(x, Wg, Wu, Wd, Wsg, Wsu, Wsd,
                                         xb, WgB, WuB, WdB, WsgB, WsuB, WsdB);
  // routed gate+up fused -> act[slot][512]
  gemm_bt<true, true, true, unsigned short><<<dim3(512, 4), 256, 0, stream>>>(
      xb, WgB, WuB, act, 0, HID, IMO, (long)IMO * HID, counts, offsets, perm);
  // routed down -> yout[slot][1024]
  gemm_bt<false, false, true, unsigned short><<<dim3(512, 8), 256, 0, stream>>>(
      act, WdB, nullptr, yout, 0, IMO, HID, (long)HID * IMO, counts, offsets, nullptr);
  // shared gate+up fused -> sact[n][1024]
  gemm_bt<true, false, false, unsigned short><<<dim3(32, 8), 256, 0, stream>>>(
      xb, WsgB, WsuB, sact, NTOK, HID, SHI, 0L, nullptr, nullptr, nullptr);
  // shared down -> d_out[n][1024] fp32 (read back by combine before overwrite)
  gemm_bt<false, false, false, float><<<dim3(32, 8), 256, 0, stream>>>(
      sact, WsdB, nullptr, out, NTOK, SHI, HID, 0L, nullptr, nullptr, nullptr);
  // out = x + shared + sum_k w_k * yout[pos]
  combine_kernel<<<NTOK, 256, 0, stream>>>(x, out, yout, topk_w, pos, out);
}

// Round 6
// 324.363 us; speedup vs baseline: 2.5693x; 1.0440x over previous
//
#include <hip/hip_runtime.h>
#include <cstdint>

typedef __bf16 bf16x8 __attribute__((ext_vector_type(8)));
typedef float f32x4 __attribute__((ext_vector_type(4)));

#define DI __device__ __forceinline__

constexpr int NTOK = 4096;   // B*S
constexpr int HID  = 1024;
constexpr int IMO  = 512;    // moe intermediate
constexpr int NEXP = 16;
constexpr int SHI  = 1024;   // shared intermediate

// async global->LDS, 16B per lane, wave-uniform LDS base (m97/m193 pattern)
#define GLOAD_LDS(g, l) __builtin_amdgcn_global_load_lds( \
    (const __attribute__((address_space(1))) unsigned int*)(const void*)(g), \
    (__attribute__((address_space(3))) unsigned int*)(void*)(l), 16, 0, 0)

DI unsigned short f2bf(float f) {
  unsigned u = __float_as_uint(f);
  u = (u + 0x7fffu + ((u >> 16) & 1u)) >> 16;   // round-to-nearest-even
  return (unsigned short)u;
}
DI float bf2f(unsigned short b) { return __uint_as_float(((unsigned)b) << 16); }

// ---------------- init / prefix / scatter ----------------
__global__ void init_counts(int* __restrict__ counts) {
  if (threadIdx.x < NEXP) counts[threadIdx.x] = 0;
}

__global__ void prefix_kernel(const int* __restrict__ counts,
                              int* __restrict__ offsets, int* __restrict__ cursor) {
  if (threadIdx.x == 0 && blockIdx.x == 0) {
    int s = 0;
    for (int e = 0; e < NEXP; ++e) { offsets[e] = s; cursor[e] = s; s += counts[e]; }
    offsets[NEXP] = s;
  }
}

__global__ __launch_bounds__(256) void scatter_kernel(
    const int* __restrict__ topk_idx, int* __restrict__ cursor,
    int* __restrict__ perm, int* __restrict__ pos) {
  int i = blockIdx.x * 256 + threadIdx.x;   // over NTOK*4
  int e = topk_idx[i];
  int slot = atomicAdd(&cursor[e], 1);
  perm[slot] = i >> 2;
  pos[i] = slot;
}

// ---------------- gate (fp64 ranking, lane-parallel, no per-lane arrays) ----------------
__global__ __launch_bounds__(256) void gate_kernel(
    const float* __restrict__ x, const float* __restrict__ gw,
    const float* __restrict__ gb, int* __restrict__ topk_idx,
    float* __restrict__ topk_w, int* __restrict__ counts) {
  const int lane = threadIdx.x & 63;
  const int n = blockIdx.x * 4 + (threadIdx.x >> 6);
  const int e = lane & 15;          // expert
  const int c = lane >> 4;          // chunk [0,4)
  const int g = e >> 2;             // group [0,4)

  const float4* x4 = (const float4*)(x + (size_t)n * HID + c * 256);
  const float4* w4 = (const float4*)(gw + (size_t)e * HID + c * 256);

  double acc0 = 0, acc1 = 0, acc2 = 0, acc3 = 0, acc4 = 0, acc5 = 0, acc6 = 0, acc7 = 0;
#pragma unroll
  for (int i = 0; i < 32; ++i) {
    float4 xa = x4[2 * i], xb = x4[2 * i + 1];
    float4 wa = w4[2 * i], wb = w4[2 * i + 1];
    acc0 += (double)xa.x * wa.x; acc1 += (double)xa.y * wa.y;
    acc2 += (double)xa.z * wa.z; acc3 += (double)xa.w * wa.w;
    acc4 += (double)xb.x * wb.x; acc5 += (double)xb.y * wb.y;
    acc6 += (double)xb.z * wb.z; acc7 += (double)xb.w * wb.w;
  }
  double L = ((acc0 + acc1) + (acc2 + acc3)) + ((acc4 + acc5) + (acc6 + acc7));
  L += __shfl_xor(L, 16);
  L += __shfl_xor(L, 32);

  double sig = 1.0 / (1.0 + exp(-L));
  double sfc = sig + (double)gb[e];

  // group score = sum of top-2 sfc within group of 4
  double o1 = __shfl_xor(sfc, 1);
  double hi = fmax(sfc, o1), lo = fmin(sfc, o1);
  double hi2 = __shfl_xor(hi, 2), lo2 = __shfl_xor(lo, 2);
  double gs = fmax(hi, hi2) + fmax(fmin(hi, hi2), fmax(lo, lo2));

  // rank my group among the 4 group scores (stable)
  double gsA = __shfl_xor(gs, 4);
  double gsB = __shfl_xor(gs, 8);
  double gsC = __shfl_xor(gs, 12);
  int grank = 0;
  grank += (gsA > gs || (gsA == gs && (g ^ 1) < g)) ? 1 : 0;
  grank += (gsB > gs || (gsB == gs && (g ^ 2) < g)) ? 1 : 0;
  grank += (gsC > gs || (gsC == gs && (g ^ 3) < g)) ? 1 : 0;
  const bool allowed = grank < 2;

  // expert rank among allowed, stable tie-break by index
  double sv = allowed ? sfc : -1e300;
  int rank = 0;
#pragma unroll
  for (int m = 1; m < 16; ++m) {
    double o = __shfl_xor(sv, m);
    int oe = e ^ m;
    rank += (o > sv || (o == sv && oe < e)) ? 1 : 0;
  }
  const bool chosen = allowed && (rank < 4);

  double t = chosen ? sig : 0.0;
  t += __shfl_xor(t, 1);
  t += __shfl_xor(t, 2);
  t += __shfl_xor(t, 4);
  t += __shfl_xor(t, 8);

  if (chosen && c == 0) {
    topk_idx[n * 4 + rank] = e;
    topk_w[n * 4 + rank] = (float)(sig / (t + 1e-20) * 2.5);
    atomicAdd(&counts[e], 1);
  }
}

// ---------------- fp32 -> bf16 convert (all arrays, one launch) ----------------
__global__ __launch_bounds__(256) void convert_all(
    const float* __restrict__ x, const float* __restrict__ wg,
    const float* __restrict__ wu, const float* __restrict__ wd,
    const float* __restrict__ sg, const float* __restrict__ su,
    const float* __restrict__ sd,
    unsigned short* __restrict__ xb, unsigned short* __restrict__ wgb,
    unsigned short* __restrict__ wub, unsigned short* __restrict__ wdb,
    unsigned short* __restrict__ sgb, unsigned short* __restrict__ sub,
    unsigned short* __restrict__ sdb) {
  long g = (long)blockIdx.x * 256 + threadIdx.x;   // float4 index, total 8126464
  const float* s; unsigned short* d; long o;
  if      (g < 1048576L) { s = x;  d = xb;  o = g; }
  else if (g < 3145728L) { s = wg; d = wgb; o = g - 1048576L; }
  else if (g < 5242880L) { s = wu; d = wub; o = g - 3145728L; }
  else if (g < 7340032L) { s = wd; d = wdb; o = g - 5242880L; }
  else if (g < 7602176L) { s = sg; d = sgb; o = g - 7340032L; }
  else if (g < 7864320L) { s = su; d = sub; o = g - 7602176L; }
  else                   { s = sd; d = sdb; o = g - 7864320L; }
  float4 v = ((const float4*)s)[o];
  ushort4 r;
  r.x = f2bf(v.x); r.y = f2bf(v.y); r.z = f2bf(v.z); r.w = f2bf(v.w);
  ((ushort4*)d)[o] = r;
}

// ---------------- merged bf16 MFMA GEMM level: routed job + shared job ----------------
// One dependency level per launch. blockIdx.x < nShared -> shared-expert GEMM;
// else routed per-expert GEMM (expert->XCD affinity preserved: 256 % 8 == 0).
// 128x128 tile, BK=32, 4 waves, 16x16x32 MFMA, global_load_lds staging.
// LDS layout per array: [row 128][32 shorts], 16B chunk (row,kl) holds data
// kc = kl ^ ((row>>1)&3)  (XOR swizzle via pre-swizzled GLOBAL source, rule-21:
// same 64B line, so coalescing intact; DMA dest stays lane-linear).
// Reader uses kc4 ^ ((r16>>1)&3): each 8-lane phase covers all 8 16B slots ->
// bank-conflict-free (round-5 residual 3.27M was this read-side conflict).
template <bool GU>
__global__ __launch_bounds__(256) void gemm_lvl(
    // routed job
    const unsigned short* __restrict__ Ar, const unsigned short* __restrict__ B0r,
    const unsigned short* __restrict__ B1r, unsigned short* __restrict__ Cr,
    int Kr, int ldcr, long eStrideB,
    const int* __restrict__ counts, const int* __restrict__ offsets,
    const int* __restrict__ perm, int useGather,
    // shared job
    const unsigned short* __restrict__ As, const unsigned short* __restrict__ B0s,
    const unsigned short* __restrict__ B1s, void* __restrict__ Cs,
    int Ms, int Ks, int ldcs, int nShared) {
  const int bx = blockIdx.x;
  const bool isShared = bx < nShared;
  int mt, y, cnt, off = 0, K, ldc;
  const unsigned short *A, *Bg, *Bu = nullptr;
  bool gather = false;
  if (isShared) {
    mt = bx & 31; y = bx >> 5;              // 32 mtiles x 8 ytiles = 256
    cnt = Ms; K = Ks; ldc = ldcs;
    A = As; Bg = B0s;
    if constexpr (GU) Bu = B1s;
  } else {
    int r = bx - nShared;
    int e = ((r & 7) << 1) | ((r >> 3) & 1); // XCD (r&7) owns experts {2c,2c+1}
    mt = (r >> 4) & 31; y = r >> 9;
    cnt = counts[e]; off = offsets[e];
    if (mt * 128 >= cnt) return;
    K = Kr; ldc = ldcr;
    A = Ar; Bg = B0r + (long)e * eStrideB;
    if constexpr (GU) Bu = B1r + (long)e * eStrideB;
    gather = (useGather != 0);
  }
  const int n0 = y * 128;

  const int tid = threadIdx.x;
  const int lane = tid & 63;
  const int wid = tid >> 6;
  const int wm = (wid >> 1) * 64, wn = (wid & 1) * 64;

  constexpr int ABYTES = 8192;                 // one array's 128x32-short tile
  constexpr int BUFB = GU ? 24576 : 16384;     // buffer stride (bytes)
  __shared__ __align__(16) unsigned char lds[2 * (GU ? 24576 : 16384)];

  // staging geometry: instr j covers chunks c in [(wid*2+j)*64, +64);
  // lane l: c = c0+l, row = c>>2, kc = (c&3) ^ ((row>>1)&3)  [XOR swizzle]
  const unsigned short* aP[2]; const unsigned short* gP[2]; const unsigned short* uP[2];
  int ldsC0[2];
#pragma unroll
  for (int j = 0; j < 2; ++j) {
    int c = (wid * 2 + j) * 64 + lane;
    int row = c >> 2;
    int kc = (c & 3) ^ ((row >> 1) & 3);
    ldsC0[j] = (wid * 2 + j) * 1024;           // byte offset of this instr's 1KB dest
    int am = mt * 128 + row;
    int amc = am < cnt ? am : cnt - 1;
    long ar;
    if (isShared)    ar = amc;
    else if (gather) ar = perm[off + amc];
    else             ar = off + amc;
    aP[j] = A + ar * (long)K + kc * 8;
    gP[j] = Bg + (long)(n0 + row) * K + kc * 8;
    if constexpr (GU) uP[j] = Bu + (long)(n0 + row) * K + kc * 8;
  }

  auto STAGE = [&](int buf, int t) {
    unsigned char* base = lds + buf * BUFB;
    const int koff = t * 32;                   // shorts
#pragma unroll
    for (int j = 0; j < 2; ++j) {
      GLOAD_LDS(aP[j] + koff, base + ldsC0[j]);
      GLOAD_LDS(gP[j] + koff, base + ABYTES + ldsC0[j]);
      if constexpr (GU) GLOAD_LDS(uP[j] + koff, base + 2 * ABYTES + ldsC0[j]);
    }
  };

  f32x4 accg[4][4];
  f32x4 accu[GU ? 4 : 1][GU ? 4 : 1];
#pragma unroll
  for (int a = 0; a < 4; ++a)
#pragma unroll
    for (int b = 0; b < 4; ++b) {
      accg[a][b] = f32x4{0.f, 0.f, 0.f, 0.f};
      if constexpr (GU) accu[a][b] = f32x4{0.f, 0.f, 0.f, 0.f};
    }

  const int r16 = lane & 15, kc4 = lane >> 4;
  const int kq = (kc4 ^ ((r16 >> 1) & 3)) * 8;   // swizzled k-chunk (shorts)
  auto COMPUTE = [&](int buf) {
    const unsigned short* bA = (const unsigned short*)(lds + buf * BUFB);
    const unsigned short* bG = bA + 4096;      // +8192 B
    const unsigned short* bU = bA + 8192;      // +16384 B
    bf16x8 af[4], gf[4], uf[4];
#pragma unroll
    for (int mi = 0; mi < 4; ++mi)
      af[mi] = *(const bf16x8*)(bA + (wm + mi * 16 + r16) * 32 + kq);
#pragma unroll
    for (int ni = 0; ni < 4; ++ni) {
      gf[ni] = *(const bf16x8*)(bG + (wn + ni * 16 + r16) * 32 + kq);
      if constexpr (GU)
        uf[ni] = *(const bf16x8*)(bU + (wn + ni * 16 + r16) * 32 + kq);
    }
#pragma unroll
    for (int mi = 0; mi < 4; ++mi)
#pragma unroll
      for (int ni = 0; ni < 4; ++ni) {
        accg[mi][ni] = __builtin_amdgcn_mfma_f32_16x16x32_bf16(af[mi], gf[ni], accg[mi][ni], 0, 0, 0);
        if constexpr (GU)
          accu[mi][ni] = __builtin_amdgcn_mfma_f32_16x16x32_bf16(af[mi], uf[ni], accu[mi][ni], 0, 0, 0);
      }
  };

  const int NT = K >> 5;
  STAGE(0, 0);
  __syncthreads();                 // drains vmcnt -> buf0 ready
  int cur = 0;
  for (int t = 0; t < NT; ++t) {
    if (t + 1 < NT) STAGE(cur ^ 1, t + 1);   // prefetch in flight under compute
    COMPUTE(cur);
    __syncthreads();               // vmcnt(0) drain + barrier -> next buf ready
    cur ^= 1;
  }

  // epilogue: C layout col=lane&15, row=(lane>>4)*4+reg  [m89-verified]
#pragma unroll
  for (int mi = 0; mi < 4; ++mi)
#pragma unroll
    for (int ni = 0; ni < 4; ++ni)
#pragma unroll
      for (int j = 0; j < 4; ++j) {
        int r = wm + mi * 16 + kc4 * 4 + j;
        int gr = mt * 128 + r;
        if (gr < cnt) {
          int c = n0 + wn + ni * 16 + r16;
          if constexpr (GU) {
            float g = accg[mi][ni][j], u = accu[mi][ni][j];
            float sg = g / (1.f + __expf(-g));       // silu
            unsigned short v = f2bf(sg * u);
            if (isShared) ((unsigned short*)Cs)[(long)gr * ldc + c] = v;
            else          Cr[((long)off + gr) * ldc + c] = v;
          } else {
            if (isShared) ((float*)Cs)[(long)gr * ldc + c] = accg[mi][ni][j];
            else          Cr[((long)off + gr) * ldc + c] = f2bf(accg[mi][ni][j]);
          }
        }
      }
}

// ---------------- final combine: out = x + shared(in d_out) + sum_k w_k*yout ----------------
__global__ __launch_bounds__(256) void combine_kernel(
    const float* __restrict__ x, const float* __restrict__ sh,
    const unsigned short* __restrict__ yout, const float* __restrict__ tw,
    const int* __restrict__ pos, float* __restrict__ out) {
  int n = blockIdx.x;                  // one block per token
  int h4 = threadIdx.x << 2;           // 256 threads * 4 floats = 1024
  float4 xv = *(const float4*)(x + (long)n * HID + h4);
  float4 sv = *(const float4*)(sh + (long)n * HID + h4);   // shared-expert result (read before write)
  float a0 = xv.x + sv.x, a1 = xv.y + sv.y, a2 = xv.z + sv.z, a3 = xv.w + sv.w;
#pragma unroll
  for (int k = 0; k < 4; ++k) {
    float w = tw[n * 4 + k];
    long slot = pos[n * 4 + k];
    ushort4 yv = *(const ushort4*)(yout + slot * HID + h4);
    a0 += w * bf2f(yv.x); a1 += w * bf2f(yv.y);
    a2 += w * bf2f(yv.z); a3 += w * bf2f(yv.w);
  }
  float4 o; o.x = a0; o.y = a1; o.z = a2; o.w = a3;
  *(float4*)(out + (long)n * HID + h4) = o;
}

// ---------------- launch ----------------
extern "C" void kernel_launch(void* const* d_in, const int* in_sizes, int n_in,
                              void* d_out, int out_size, void* d_ws, size_t ws_size,
                              hipStream_t stream) {
  (void)in_sizes; (void)n_in; (void)out_size; (void)ws_size;
  const float* x   = (const float*)d_in[0];
  const float* gw  = (const float*)d_in[1];
  const float* gb  = (const float*)d_in[2];
  const float* Wg  = (const float*)d_in[3];
  const float* Wu  = (const float*)d_in[4];
  const float* Wd  = (const float*)d_in[5];
  const float* Wsg = (const float*)d_in[6];
  const float* Wsu = (const float*)d_in[7];
  const float* Wsd = (const float*)d_in[8];
  float* out = (float*)d_out;

  // ---- workspace layout (big buffers start at 512 KiB; small region ends 262400) ----
  char* w = (char*)d_ws;
  int*   counts   = (int*)(w + 0);                    // 64 B
  int*   cursor   = (int*)(w + 64);                   // 64 B
  int*   offsets  = (int*)(w + 128);                  // 128 B (17 ints)
  int*   topk_idx = (int*)(w + 256);                  // 65536 B
  float* topk_w   = (float*)(w + 256 + 65536);        // 65536 B
  int*   perm     = (int*)(w + 256 + 131072);         // 65536 B
  int*   pos      = (int*)(w + 256 + 196608);         // 65536 B
  size_t o = 524288;                                  // big buffers from 512 KiB
  unsigned short* xb   = (unsigned short*)(w + o); o += (size_t)NTOK * HID * 2;       // 8 MB
  unsigned short* WgB  = (unsigned short*)(w + o); o += (size_t)NEXP * IMO * HID * 2; // 16 MB
  unsigned short* WuB  = (unsigned short*)(w + o); o += (size_t)NEXP * IMO * HID * 2; // 16 MB
  unsigned short* WdB  = (unsigned short*)(w + o); o += (size_t)NEXP * HID * IMO * 2; // 16 MB
  unsigned short* WsgB = (unsigned short*)(w + o); o += (size_t)SHI * HID * 2;        // 2 MB
  unsigned short* WsuB = (unsigned short*)(w + o); o += (size_t)SHI * HID * 2;        // 2 MB
  unsigned short* WsdB = (unsigned short*)(w + o); o += (size_t)HID * SHI * 2;        // 2 MB
  unsigned short* act  = (unsigned short*)(w + o); o += (size_t)NTOK * 4 * IMO * 2;   // 16 MB
  unsigned short* yout = (unsigned short*)(w + o); o += (size_t)NTOK * 4 * HID * 2;   // 32 MB
  unsigned short* sact = (unsigned short*)(w + o); o += (size_t)NTOK * SHI * 2;       // 8 MB
  // total ws use ~118.5 MiB; shared-expert fp32 output goes directly to d_out

  init_counts<<<1, 64, 0, stream>>>(counts);
  gate_kernel<<<NTOK / 4, 256, 0, stream>>>(x, gw, gb, topk_idx, topk_w, counts);
  prefix_kernel<<<1, 64, 0, stream>>>(counts, offsets, cursor);
  scatter_kernel<<<NTOK * 4 / 256, 256, 0, stream>>>(topk_idx, cursor, perm, pos);
  convert_all<<<31744, 256, 0, stream>>>(x, Wg, Wu, Wd, Wsg, Wsu, Wsd,
                                         xb, WgB, WuB, WdB, WsgB, WsuB, WsdB);
  // Level 1: routed gate+up (gather) + shared gate+up, one launch.
  // x = 256 shared blocks + 2048 routed slots (e,mt 512 x ny 4)
  gemm_lvl<true><<<256 + 2048, 256, 0, stream>>>(
      xb, WgB, WuB, act, HID, IMO, (long)IMO * HID, counts, offsets, perm, 1,
      xb, WsgB, WsuB, sact, NTOK, HID, SHI, 256);
  // Level 2: routed down + shared down (fp32 to d_out), one launch.
  // x = 256 shared blocks + 4096 routed slots (e,mt 512 x ny 8)
  gemm_lvl<false><<<256 + 4096, 256, 0, stream>>>(
      act, WdB, nullptr, yout, IMO, HID, (long)HID * IMO, counts, offsets, nullptr, 0,
      sact, WsdB, nullptr, out, NTOK, SHI, HID, 256);
  // out = x + shared + sum_k w_k * yout[pos]
  combine_kernel<<<NTOK, 256, 0, stream>>>(x, out, yout, topk_w, pos, out);
}

// Round 7
// 308.281 us; speedup vs baseline: 2.7033x; 1.0522x over previous
//
#include <hip/hip_runtime.h>
#include <cstdint>

typedef __bf16 bf16x8 __attribute__((ext_vector_type(8)));
typedef float f32x4 __attribute__((ext_vector_type(4)));

#define DI __device__ __forceinline__

constexpr int NTOK = 4096;   // B*S
constexpr int HID  = 1024;
constexpr int IMO  = 512;    // moe intermediate
constexpr int NEXP = 16;
constexpr int SHI  = 1024;   // shared intermediate

// async global->LDS, 16B per lane, wave-uniform LDS base (m97/m193 pattern)
#define GLOAD_LDS(g, l) __builtin_amdgcn_global_load_lds( \
    (const __attribute__((address_space(1))) unsigned int*)(const void*)(g), \
    (__attribute__((address_space(3))) unsigned int*)(void*)(l), 16, 0, 0)

DI unsigned short f2bf(float f) {
  unsigned u = __float_as_uint(f);
  u = (u + 0x7fffu + ((u >> 16) & 1u)) >> 16;   // round-to-nearest-even
  return (unsigned short)u;
}
DI float bf2f(unsigned short b) { return __uint_as_float(((unsigned)b) << 16); }

// ---------------- init / prefix / scatter ----------------
__global__ void init_counts(int* __restrict__ counts) {
  if (threadIdx.x < NEXP) counts[threadIdx.x] = 0;
}

__global__ void prefix_kernel(const int* __restrict__ counts,
                              int* __restrict__ offsets, int* __restrict__ cursor) {
  if (threadIdx.x == 0 && blockIdx.x == 0) {
    int s = 0;
    for (int e = 0; e < NEXP; ++e) { offsets[e] = s; cursor[e] = s; s += counts[e]; }
    offsets[NEXP] = s;
  }
}

__global__ __launch_bounds__(256) void scatter_kernel(
    const int* __restrict__ topk_idx, int* __restrict__ cursor,
    int* __restrict__ perm, int* __restrict__ pos) {
  int i = blockIdx.x * 256 + threadIdx.x;   // over NTOK*4
  int e = topk_idx[i];
  int slot = atomicAdd(&cursor[e], 1);
  perm[slot] = i >> 2;
  pos[i] = slot;
}

// ---------------- gate (fp64 ranking, lane-parallel, no per-lane arrays) ----------------
__global__ __launch_bounds__(256) void gate_kernel(
    const float* __restrict__ x, const float* __restrict__ gw,
    const float* __restrict__ gb, int* __restrict__ topk_idx,
    float* __restrict__ topk_w, int* __restrict__ counts) {
  const int lane = threadIdx.x & 63;
  const int n = blockIdx.x * 4 + (threadIdx.x >> 6);
  const int e = lane & 15;          // expert
  const int c = lane >> 4;          // chunk [0,4)
  const int g = e >> 2;             // group [0,4)

  const float4* x4 = (const float4*)(x + (size_t)n * HID + c * 256);
  const float4* w4 = (const float4*)(gw + (size_t)e * HID + c * 256);

  double acc0 = 0, acc1 = 0, acc2 = 0, acc3 = 0, acc4 = 0, acc5 = 0, acc6 = 0, acc7 = 0;
#pragma unroll
  for (int i = 0; i < 32; ++i) {
    float4 xa = x4[2 * i], xb = x4[2 * i + 1];
    float4 wa = w4[2 * i], wb = w4[2 * i + 1];
    acc0 += (double)xa.x * wa.x; acc1 += (double)xa.y * wa.y;
    acc2 += (double)xa.z * wa.z; acc3 += (double)xa.w * wa.w;
    acc4 += (double)xb.x * wb.x; acc5 += (double)xb.y * wb.y;
    acc6 += (double)xb.z * wb.z; acc7 += (double)xb.w * wb.w;
  }
  double L = ((acc0 + acc1) + (acc2 + acc3)) + ((acc4 + acc5) + (acc6 + acc7));
  L += __shfl_xor(L, 16);
  L += __shfl_xor(L, 32);

  double sig = 1.0 / (1.0 + exp(-L));
  double sfc = sig + (double)gb[e];

  // group score = sum of top-2 sfc within group of 4
  double o1 = __shfl_xor(sfc, 1);
  double hi = fmax(sfc, o1), lo = fmin(sfc, o1);
  double hi2 = __shfl_xor(hi, 2), lo2 = __shfl_xor(lo, 2);
  double gs = fmax(hi, hi2) + fmax(fmin(hi, hi2), fmax(lo, lo2));

  // rank my group among the 4 group scores (stable)
  double gsA = __shfl_xor(gs, 4);
  double gsB = __shfl_xor(gs, 8);
  double gsC = __shfl_xor(gs, 12);
  int grank = 0;
  grank += (gsA > gs || (gsA == gs && (g ^ 1) < g)) ? 1 : 0;
  grank += (gsB > gs || (gsB == gs && (g ^ 2) < g)) ? 1 : 0;
  grank += (gsC > gs || (gsC == gs && (g ^ 3) < g)) ? 1 : 0;
  const bool allowed = grank < 2;

  // expert rank among allowed, stable tie-break by index
  double sv = allowed ? sfc : -1e300;
  int rank = 0;
#pragma unroll
  for (int m = 1; m < 16; ++m) {
    double o = __shfl_xor(sv, m);
    int oe = e ^ m;
    rank += (o > sv || (o == sv && oe < e)) ? 1 : 0;
  }
  const bool chosen = allowed && (rank < 4);

  double t = chosen ? sig : 0.0;
  t += __shfl_xor(t, 1);
  t += __shfl_xor(t, 2);
  t += __shfl_xor(t, 4);
  t += __shfl_xor(t, 8);

  if (chosen && c == 0) {
    topk_idx[n * 4 + rank] = e;
    topk_w[n * 4 + rank] = (float)(sig / (t + 1e-20) * 2.5);
    atomicAdd(&counts[e], 1);
  }
}

// ---------------- fp32 -> bf16 convert (all arrays, one launch) ----------------
__global__ __launch_bounds__(256) void convert_all(
    const float* __restrict__ x, const float* __restrict__ wg,
    const float* __restrict__ wu, const float* __restrict__ wd,
    const float* __restrict__ sg, const float* __restrict__ su,
    const float* __restrict__ sd,
    unsigned short* __restrict__ xb, unsigned short* __restrict__ wgb,
    unsigned short* __restrict__ wub, unsigned short* __restrict__ wdb,
    unsigned short* __restrict__ sgb, unsigned short* __restrict__ sub,
    unsigned short* __restrict__ sdb) {
  long g = (long)blockIdx.x * 256 + threadIdx.x;   // float4 index, total 8126464
  const float* s; unsigned short* d; long o;
  if      (g < 1048576L) { s = x;  d = xb;  o = g; }
  else if (g < 3145728L) { s = wg; d = wgb; o = g - 1048576L; }
  else if (g < 5242880L) { s = wu; d = wub; o = g - 3145728L; }
  else if (g < 7340032L) { s = wd; d = wdb; o = g - 5242880L; }
  else if (g < 7602176L) { s = sg; d = sgb; o = g - 7340032L; }
  else if (g < 7864320L) { s = su; d = sub; o = g - 7602176L; }
  else                   { s = sd; d = sdb; o = g - 7864320L; }
  float4 v = ((const float4*)s)[o];
  ushort4 r;
  r.x = f2bf(v.x); r.y = f2bf(v.y); r.z = f2bf(v.z); r.w = f2bf(v.w);
  ((ushort4*)d)[o] = r;
}

// ---------------- merged bf16 MFMA GEMM level: routed job + shared job ----------------
// One dependency level per launch. blockIdx.x < nShared -> shared GEMM; else routed
// (expert->XCD affinity). 128x128 tile, BK=32, 4 waves, 16x16x32 MFMA.
// Staging: global_load_lds width=16, XOR k-swizzle via pre-swizzled global source
// (read side uses kc4 ^ ((r16>>1)&3)) -- bank-conflict-free both sides (round-6: 0).
// Round-7: depth-3 pipeline, counted vmcnt (T4) + raw s_barrier -- the 2-phase
// __syncthreads drained vmcnt(0) every K-step, exposing full HBM latency against
// only ~160cy of MFMA (MfmaUtil 17.5%). Now tiles t+1,t+2 stay in flight across
// the barrier; each tile's loads get ~2 compute phases to land.
template <bool GU>
__global__ __launch_bounds__(256) void gemm_lvl(
    // routed job
    const unsigned short* __restrict__ Ar, const unsigned short* __restrict__ B0r,
    const unsigned short* __restrict__ B1r, unsigned short* __restrict__ Cr,
    int Kr, int ldcr, long eStrideB,
    const int* __restrict__ counts, const int* __restrict__ offsets,
    const int* __restrict__ perm, int useGather,
    // shared job
    const unsigned short* __restrict__ As, const unsigned short* __restrict__ B0s,
    const unsigned short* __restrict__ B1s, void* __restrict__ Cs,
    int Ms, int Ks, int ldcs, int nShared) {
  const int bx = blockIdx.x;
  const bool isShared = bx < nShared;
  int mt, y, cnt, off = 0, K, ldc;
  const unsigned short *A, *Bg, *Bu = nullptr;
  bool gather = false;
  if (isShared) {
    mt = bx & 31; y = bx >> 5;              // 32 mtiles x 8 ytiles = 256
    cnt = Ms; K = Ks; ldc = ldcs;
    A = As; Bg = B0s;
    if constexpr (GU) Bu = B1s;
  } else {
    int r = bx - nShared;
    int e = ((r & 7) << 1) | ((r >> 3) & 1); // XCD (r&7) owns experts {2c,2c+1}
    mt = (r >> 4) & 31; y = r >> 9;
    cnt = counts[e]; off = offsets[e];
    if (mt * 128 >= cnt) return;
    K = Kr; ldc = ldcr;
    A = Ar; Bg = B0r + (long)e * eStrideB;
    if constexpr (GU) Bu = B1r + (long)e * eStrideB;
    gather = (useGather != 0);
  }
  const int n0 = y * 128;

  const int tid = threadIdx.x;
  const int lane = tid & 63;
  const int wid = tid >> 6;
  const int wm = (wid >> 1) * 64, wn = (wid & 1) * 64;

  constexpr int ABYTES = 8192;                 // one array's 128x32-short tile
  constexpr int BUFB = GU ? 24576 : 16384;     // buffer stride (bytes)
  __shared__ __align__(16) unsigned char lds[3 * (GU ? 24576 : 16384)];

  // staging geometry: instr j covers chunks c in [(wid*2+j)*64, +64);
  // lane l: c = c0+l, row = c>>2, kc = (c&3) ^ ((row>>1)&3)  [XOR swizzle]
  const unsigned short* aP[2]; const unsigned short* gP[2]; const unsigned short* uP[2];
  int ldsC0[2];
#pragma unroll
  for (int j = 0; j < 2; ++j) {
    int c = (wid * 2 + j) * 64 + lane;
    int row = c >> 2;
    int kc = (c & 3) ^ ((row >> 1) & 3);
    ldsC0[j] = (wid * 2 + j) * 1024;           // byte offset of this instr's 1KB dest
    int am = mt * 128 + row;
    int amc = am < cnt ? am : cnt - 1;
    long ar;
    if (isShared)    ar = amc;
    else if (gather) ar = perm[off + amc];
    else             ar = off + amc;
    aP[j] = A + ar * (long)K + kc * 8;
    gP[j] = Bg + (long)(n0 + row) * K + kc * 8;
    if constexpr (GU) uP[j] = Bu + (long)(n0 + row) * K + kc * 8;
  }

  auto STAGE = [&](int buf, int t) {
    unsigned char* base = lds + buf * BUFB;
    const int koff = t * 32;                   // shorts
#pragma unroll
    for (int j = 0; j < 2; ++j) {
      GLOAD_LDS(aP[j] + koff, base + ldsC0[j]);
      GLOAD_LDS(gP[j] + koff, base + ABYTES + ldsC0[j]);
      if constexpr (GU) GLOAD_LDS(uP[j] + koff, base + 2 * ABYTES + ldsC0[j]);
    }
  };

  f32x4 accg[4][4];
  f32x4 accu[GU ? 4 : 1][GU ? 4 : 1];
#pragma unroll
  for (int a = 0; a < 4; ++a)
#pragma unroll
    for (int b = 0; b < 4; ++b) {
      accg[a][b] = f32x4{0.f, 0.f, 0.f, 0.f};
      if constexpr (GU) accu[a][b] = f32x4{0.f, 0.f, 0.f, 0.f};
    }

  const int r16 = lane & 15, kc4 = lane >> 4;
  const int kq = (kc4 ^ ((r16 >> 1) & 3)) * 8;   // swizzled k-chunk (shorts)
  auto COMPUTE = [&](int buf) {
    const unsigned short* bA = (const unsigned short*)(lds + buf * BUFB);
    const unsigned short* bG = bA + 4096;      // +8192 B
    const unsigned short* bU = bA + 8192;      // +16384 B
    bf16x8 af[4], gf[4], uf[4];
#pragma unroll
    for (int mi = 0; mi < 4; ++mi)
      af[mi] = *(const bf16x8*)(bA + (wm + mi * 16 + r16) * 32 + kq);
#pragma unroll
    for (int ni = 0; ni < 4; ++ni) {
      gf[ni] = *(const bf16x8*)(bG + (wn + ni * 16 + r16) * 32 + kq);
      if constexpr (GU)
        uf[ni] = *(const bf16x8*)(bU + (wn + ni * 16 + r16) * 32 + kq);
    }
#pragma unroll
    for (int mi = 0; mi < 4; ++mi)
#pragma unroll
      for (int ni = 0; ni < 4; ++ni) {
        accg[mi][ni] = __builtin_amdgcn_mfma_f32_16x16x32_bf16(af[mi], gf[ni], accg[mi][ni], 0, 0, 0);
        if constexpr (GU)
          accu[mi][ni] = __builtin_amdgcn_mfma_f32_16x16x32_bf16(af[mi], uf[ni], accu[mi][ni], 0, 0, 0);
      }
  };

  // ---- depth-3 pipeline, counted vmcnt (loads/STAGE: GU=6, else=4) ----
  const int NT = K >> 5;                 // NT >= 16 always here
  STAGE(0, 0);
  STAGE(1, 1);
  STAGE(2, 2);
  int cur = 0;
  for (int t = 0; t < NT; ++t) {
    // wait until tile t's loads (oldest) retire; keep t+1,t+2 in flight
    if (t + 2 < NT) {
      if constexpr (GU) asm volatile("s_waitcnt vmcnt(12)" ::: "memory");
      else              asm volatile("s_waitcnt vmcnt(8)"  ::: "memory");
    } else if (t + 2 == NT) {
      if constexpr (GU) asm volatile("s_waitcnt vmcnt(6)" ::: "memory");
      else              asm volatile("s_waitcnt vmcnt(4)" ::: "memory");
    } else {
      asm volatile("s_waitcnt vmcnt(0)" ::: "memory");
    }
    __builtin_amdgcn_s_barrier();        // all waves' tile-t loads now visible
    COMPUTE(cur);
    __builtin_amdgcn_s_barrier();        // all waves done reading buf cur
    if (t + 3 < NT) STAGE(cur, t + 3);   // refill freed buffer
    cur = (cur == 2) ? 0 : cur + 1;
  }

  // epilogue: C layout col=lane&15, row=(lane>>4)*4+reg  [m89-verified]
#pragma unroll
  for (int mi = 0; mi < 4; ++mi)
#pragma unroll
    for (int ni = 0; ni < 4; ++ni)
#pragma unroll
      for (int j = 0; j < 4; ++j) {
        int r = wm + mi * 16 + kc4 * 4 + j;
        int gr = mt * 128 + r;
        if (gr < cnt) {
          int c = n0 + wn + ni * 16 + r16;
          if constexpr (GU) {
            float g = accg[mi][ni][j], u = accu[mi][ni][j];
            float sg = g / (1.f + __expf(-g));       // silu
            unsigned short v = f2bf(sg * u);
            if (isShared) ((unsigned short*)Cs)[(long)gr * ldc + c] = v;
            else          Cr[((long)off + gr) * ldc + c] = v;
          } else {
            if (isShared) ((float*)Cs)[(long)gr * ldc + c] = accg[mi][ni][j];
            else          Cr[((long)off + gr) * ldc + c] = f2bf(accg[mi][ni][j]);
          }
        }
      }
}

// ---------------- final combine: out = x + shared(in d_out) + sum_k w_k*yout ----------------
__global__ __launch_bounds__(256) void combine_kernel(
    const float* __restrict__ x, const float* __restrict__ sh,
    const unsigned short* __restrict__ yout, const float* __restrict__ tw,
    const int* __restrict__ pos, float* __restrict__ out) {
  int n = blockIdx.x;                  // one block per token
  int h4 = threadIdx.x << 2;           // 256 threads * 4 floats = 1024
  float4 xv = *(const float4*)(x + (long)n * HID + h4);
  float4 sv = *(const float4*)(sh + (long)n * HID + h4);   // shared-expert result (read before write)
  float a0 = xv.x + sv.x, a1 = xv.y + sv.y, a2 = xv.z + sv.z, a3 = xv.w + sv.w;
#pragma unroll
  for (int k = 0; k < 4; ++k) {
    float w = tw[n * 4 + k];
    long slot = pos[n * 4 + k];
    ushort4 yv = *(const ushort4*)(yout + slot * HID + h4);
    a0 += w * bf2f(yv.x); a1 += w * bf2f(yv.y);
    a2 += w * bf2f(yv.z); a3 += w * bf2f(yv.w);
  }
  float4 o; o.x = a0; o.y = a1; o.z = a2; o.w = a3;
  *(float4*)(out + (long)n * HID + h4) = o;
}

// ---------------- launch ----------------
extern "C" void kernel_launch(void* const* d_in, const int* in_sizes, int n_in,
                              void* d_out, int out_size, void* d_ws, size_t ws_size,
                              hipStream_t stream) {
  (void)in_sizes; (void)n_in; (void)out_size; (void)ws_size;
  const float* x   = (const float*)d_in[0];
  const float* gw  = (const float*)d_in[1];
  const float* gb  = (const float*)d_in[2];
  const float* Wg  = (const float*)d_in[3];
  const float* Wu  = (const float*)d_in[4];
  const float* Wd  = (const float*)d_in[5];
  const float* Wsg = (const float*)d_in[6];
  const float* Wsu = (const float*)d_in[7];
  const float* Wsd = (const float*)d_in[8];
  float* out = (float*)d_out;

  // ---- workspace layout (big buffers start at 512 KiB; small region ends 262400) ----
  char* w = (char*)d_ws;
  int*   counts   = (int*)(w + 0);                    // 64 B
  int*   cursor   = (int*)(w + 64);                   // 64 B
  int*   offsets  = (int*)(w + 128);                  // 128 B (17 ints)
  int*   topk_idx = (int*)(w + 256);                  // 65536 B
  float* topk_w   = (float*)(w + 256 + 65536);        // 65536 B
  int*   perm     = (int*)(w + 256 + 131072);         // 65536 B
  int*   pos      = (int*)(w + 256 + 196608);         // 65536 B
  size_t o = 524288;                                  // big buffers from 512 KiB
  unsigned short* xb   = (unsigned short*)(w + o); o += (size_t)NTOK * HID * 2;       // 8 MB
  unsigned short* WgB  = (unsigned short*)(w + o); o += (size_t)NEXP * IMO * HID * 2; // 16 MB
  unsigned short* WuB  = (unsigned short*)(w + o); o += (size_t)NEXP * IMO * HID * 2; // 16 MB
  unsigned short* WdB  = (unsigned short*)(w + o); o += (size_t)NEXP * HID * IMO * 2; // 16 MB
  unsigned short* WsgB = (unsigned short*)(w + o); o += (size_t)SHI * HID * 2;        // 2 MB
  unsigned short* WsuB = (unsigned short*)(w + o); o += (size_t)SHI * HID * 2;        // 2 MB
  unsigned short* WsdB = (unsigned short*)(w + o); o += (size_t)HID * SHI * 2;        // 2 MB
  unsigned short* act  = (unsigned short*)(w + o); o += (size_t)NTOK * 4 * IMO * 2;   // 16 MB
  unsigned short* yout = (unsigned short*)(w + o); o += (size_t)NTOK * 4 * HID * 2;   // 32 MB
  unsigned short* sact = (unsigned short*)(w + o); o += (size_t)NTOK * SHI * 2;       // 8 MB
  // total ws use ~118.5 MiB; shared-expert fp32 output goes directly to d_out

  init_counts<<<1, 64, 0, stream>>>(counts);
  gate_kernel<<<NTOK / 4, 256, 0, stream>>>(x, gw, gb, topk_idx, topk_w, counts);
  prefix_kernel<<<1, 64, 0, stream>>>(counts, offsets, cursor);
  scatter_kernel<<<NTOK * 4 / 256, 256, 0, stream>>>(topk_idx, cursor, perm, pos);
  convert_all<<<31744, 256, 0, stream>>>(x, Wg, Wu, Wd, Wsg, Wsu, Wsd,
                                         xb, WgB, WuB, WdB, WsgB, WsuB, WsdB);
  // Level 1: routed gate+up (gather) + shared gate+up, one launch.
  gemm_lvl<true><<<256 + 2048, 256, 0, stream>>>(
      xb, WgB, WuB, act, HID, IMO, (long)IMO * HID, counts, offsets, perm, 1,
      xb, WsgB, WsuB, sact, NTOK, HID, SHI, 256);
  // Level 2: routed down + shared down (fp32 to d_out), one launch.
  gemm_lvl<false><<<256 + 4096, 256, 0, stream>>>(
      act, WdB, nullptr, yout, IMO, HID, (long)HID * IMO, counts, offsets, nullptr, 0,
      sact, WsdB, nullptr, out, NTOK, SHI, HID, 256);
  // out = x + shared + sum_k w_k * yout[pos]
  combine_kernel<<<NTOK, 256, 0, stream>>>(x, out, yout, topk_w, pos, out);
}

// Round 8
// 280.992 us; speedup vs baseline: 2.9658x; 1.0971x over previous
//
#include <hip/hip_runtime.h>
#include <cstdint>

typedef __bf16 bf16x8 __attribute__((ext_vector_type(8)));
typedef float f32x4 __attribute__((ext_vector_type(4)));

#define DI __device__ __forceinline__

constexpr int NTOK = 4096;   // B*S
constexpr int HID  = 1024;
constexpr int IMO  = 512;    // moe intermediate
constexpr int NEXP = 16;
constexpr int SHI  = 1024;   // shared intermediate

// async global->LDS, 16B per lane, wave-uniform LDS base (m97/m193 pattern)
#define GLOAD_LDS(g, l) __builtin_amdgcn_global_load_lds( \
    (const __attribute__((address_space(1))) unsigned int*)(const void*)(g), \
    (__attribute__((address_space(3))) unsigned int*)(void*)(l), 16, 0, 0)

DI unsigned short f2bf(float f) {
  unsigned u = __float_as_uint(f);
  u = (u + 0x7fffu + ((u >> 16) & 1u)) >> 16;   // round-to-nearest-even
  return (unsigned short)u;
}
DI float bf2f(unsigned short b) { return __uint_as_float(((unsigned)b) << 16); }

// ---------------- init / prefix / scatter ----------------
__global__ void init_counts(int* __restrict__ counts) {
  if (threadIdx.x < NEXP) counts[threadIdx.x] = 0;
}

__global__ void prefix_kernel(const int* __restrict__ counts,
                              int* __restrict__ offsets, int* __restrict__ cursor) {
  if (threadIdx.x == 0 && blockIdx.x == 0) {
    int s = 0;
    for (int e = 0; e < NEXP; ++e) { offsets[e] = s; cursor[e] = s; s += counts[e]; }
    offsets[NEXP] = s;
  }
}

__global__ __launch_bounds__(256) void scatter_kernel(
    const int* __restrict__ topk_idx, int* __restrict__ cursor,
    int* __restrict__ perm, int* __restrict__ pos) {
  int i = blockIdx.x * 256 + threadIdx.x;   // over NTOK*4
  int e = topk_idx[i];
  int slot = atomicAdd(&cursor[e], 1);
  perm[slot] = i >> 2;
  pos[i] = slot;
}

// ---------------- gate (fp64 ranking, lane-parallel, no per-lane arrays) ----------------
__global__ __launch_bounds__(256) void gate_kernel(
    const float* __restrict__ x, const float* __restrict__ gw,
    const float* __restrict__ gb, int* __restrict__ topk_idx,
    float* __restrict__ topk_w, int* __restrict__ counts) {
  const int lane = threadIdx.x & 63;
  const int n = blockIdx.x * 4 + (threadIdx.x >> 6);
  const int e = lane & 15;          // expert
  const int c = lane >> 4;          // chunk [0,4)
  const int g = e >> 2;             // group [0,4)

  const float4* x4 = (const float4*)(x + (size_t)n * HID + c * 256);
  const float4* w4 = (const float4*)(gw + (size_t)e * HID + c * 256);

  double acc0 = 0, acc1 = 0, acc2 = 0, acc3 = 0, acc4 = 0, acc5 = 0, acc6 = 0, acc7 = 0;
#pragma unroll
  for (int i = 0; i < 32; ++i) {
    float4 xa = x4[2 * i], xb = x4[2 * i + 1];
    float4 wa = w4[2 * i], wb = w4[2 * i + 1];
    acc0 += (double)xa.x * wa.x; acc1 += (double)xa.y * wa.y;
    acc2 += (double)xa.z * wa.z; acc3 += (double)xa.w * wa.w;
    acc4 += (double)xb.x * wb.x; acc5 += (double)xb.y * wb.y;
    acc6 += (double)xb.z * wb.z; acc7 += (double)xb.w * wb.w;
  }
  double L = ((acc0 + acc1) + (acc2 + acc3)) + ((acc4 + acc5) + (acc6 + acc7));
  L += __shfl_xor(L, 16);
  L += __shfl_xor(L, 32);

  double sig = 1.0 / (1.0 + exp(-L));
  double sfc = sig + (double)gb[e];

  // group score = sum of top-2 sfc within group of 4
  double o1 = __shfl_xor(sfc, 1);
  double hi = fmax(sfc, o1), lo = fmin(sfc, o1);
  double hi2 = __shfl_xor(hi, 2), lo2 = __shfl_xor(lo, 2);
  double gs = fmax(hi, hi2) + fmax(fmin(hi, hi2), fmax(lo, lo2));

  // rank my group among the 4 group scores (stable)
  double gsA = __shfl_xor(gs, 4);
  double gsB = __shfl_xor(gs, 8);
  double gsC = __shfl_xor(gs, 12);
  int grank = 0;
  grank += (gsA > gs || (gsA == gs && (g ^ 1) < g)) ? 1 : 0;
  grank += (gsB > gs || (gsB == gs && (g ^ 2) < g)) ? 1 : 0;
  grank += (gsC > gs || (gsC == gs && (g ^ 3) < g)) ? 1 : 0;
  const bool allowed = grank < 2;

  // expert rank among allowed, stable tie-break by index
  double sv = allowed ? sfc : -1e300;
  int rank = 0;
#pragma unroll
  for (int m = 1; m < 16; ++m) {
    double o = __shfl_xor(sv, m);
    int oe = e ^ m;
    rank += (o > sv || (o == sv && oe < e)) ? 1 : 0;
  }
  const bool chosen = allowed && (rank < 4);

  double t = chosen ? sig : 0.0;
  t += __shfl_xor(t, 1);
  t += __shfl_xor(t, 2);
  t += __shfl_xor(t, 4);
  t += __shfl_xor(t, 8);

  if (chosen && c == 0) {
    topk_idx[n * 4 + rank] = e;
    topk_w[n * 4 + rank] = (float)(sig / (t + 1e-20) * 2.5);
    atomicAdd(&counts[e], 1);
  }
}

// ---------------- fp32 -> bf16 convert (all arrays, one launch) ----------------
__global__ __launch_bounds__(256) void convert_all(
    const float* __restrict__ x, const float* __restrict__ wg,
    const float* __restrict__ wu, const float* __restrict__ wd,
    const float* __restrict__ sg, const float* __restrict__ su,
    const float* __restrict__ sd,
    unsigned short* __restrict__ xb, unsigned short* __restrict__ wgb,
    unsigned short* __restrict__ wub, unsigned short* __restrict__ wdb,
    unsigned short* __restrict__ sgb, unsigned short* __restrict__ sub,
    unsigned short* __restrict__ sdb) {
  long g = (long)blockIdx.x * 256 + threadIdx.x;   // float4 index, total 8126464
  const float* s; unsigned short* d; long o;
  if      (g < 1048576L) { s = x;  d = xb;  o = g; }
  else if (g < 3145728L) { s = wg; d = wgb; o = g - 1048576L; }
  else if (g < 5242880L) { s = wu; d = wub; o = g - 3145728L; }
  else if (g < 7340032L) { s = wd; d = wdb; o = g - 5242880L; }
  else if (g < 7602176L) { s = sg; d = sgb; o = g - 7340032L; }
  else if (g < 7864320L) { s = su; d = sub; o = g - 7602176L; }
  else                   { s = sd; d = sdb; o = g - 7864320L; }
  float4 v = ((const float4*)s)[o];
  ushort4 r;
  r.x = f2bf(v.x); r.y = f2bf(v.y); r.z = f2bf(v.z); r.w = f2bf(v.w);
  ((ushort4*)d)[o] = r;
}

// ---------------- merged bf16 MFMA GEMM level: routed job + shared job ----------------
// Round-8: BM=256, 8 waves (512 thr). Per-wave regs (~264, acc=128 AGPR) cap HW at
// 2 waves/SIMD regardless of LDS, so raise FLOP/staged-byte instead of TLP:
// intensity BM*BN/(BM+BN): GU 85->128, down 64->85; barriers per MFMA halve.
// Depth-2 counted-vmcnt pipeline (per-wave loads: GU 4, down 3; never drain to 0
// mid-loop). XOR k-swizzle staging/read unchanged (bank-conflict 0, round-6/7).
template <bool GU>
__global__ __launch_bounds__(512) void gemm_lvl(
    // routed job
    const unsigned short* __restrict__ Ar, const unsigned short* __restrict__ B0r,
    const unsigned short* __restrict__ B1r, unsigned short* __restrict__ Cr,
    int Kr, int ldcr, long eStrideB,
    const int* __restrict__ counts, const int* __restrict__ offsets,
    const int* __restrict__ perm, int useGather,
    // shared job
    const unsigned short* __restrict__ As, const unsigned short* __restrict__ B0s,
    const unsigned short* __restrict__ B1s, void* __restrict__ Cs,
    int Ms, int Ks, int ldcs, int nShared) {
  const int bx = blockIdx.x;
  const bool isShared = bx < nShared;
  int mt, y, cnt, off = 0, K, ldc;
  const unsigned short *A, *Bg, *Bu = nullptr;
  bool gather = false;
  if (isShared) {
    mt = bx & 15; y = bx >> 4;              // 16 mtiles(256) x ny
    cnt = Ms; K = Ks; ldc = ldcs;
    A = As; Bg = B0s;
    if constexpr (GU) Bu = B1s;
  } else {
    int r = bx - nShared;
    int e = ((r & 7) << 1) | ((r >> 3) & 1); // XCD (r&7) owns experts {2c,2c+1}
    mt = (r >> 4) & 15; y = r >> 8;
    cnt = counts[e]; off = offsets[e];
    if (mt * 256 >= cnt) return;
    K = Kr; ldc = ldcr;
    A = Ar; Bg = B0r + (long)e * eStrideB;
    if constexpr (GU) Bu = B1r + (long)e * eStrideB;
    gather = (useGather != 0);
  }
  const int n0 = y * 128;

  const int tid = threadIdx.x;
  const int lane = tid & 63;
  const int wid = tid >> 6;                  // [0,8)
  const int wm = (wid >> 1) * 64, wn = (wid & 1) * 64;

  constexpr int ABYTES = 16384;              // A region: 256 rows x 32 shorts
  constexpr int BBYTES = 8192;               // each B region: 128 rows x 32 shorts
  constexpr int BUFB = GU ? 32768 : 24576;   // buffer stride (bytes)
  __shared__ __align__(16) unsigned char lds[2 * (GU ? 32768 : 24576)];

  // ---- staging geometry ----
  // A: 1024 chunks(16B) -> 16 DMA instrs, 2/wave: instr i = wid*2+j covers
  //   chunks [i*64, i*64+64); lane l: c = i*64+l, row=c>>2, kc=(c&3)^((row>>1)&3).
  // B (g,u): 512 chunks -> 8 instrs, 1/wave: c = wid*64+lane.
  const unsigned short* aP[2]; const unsigned short* gP; const unsigned short* uP = nullptr;
  int aD[2], bD;
#pragma unroll
  for (int j = 0; j < 2; ++j) {
    int c = (wid * 2 + j) * 64 + lane;
    int row = c >> 2;
    int kc = (c & 3) ^ ((row >> 1) & 3);
    aD[j] = (wid * 2 + j) * 1024;
    int am = mt * 256 + row;
    int amc = am < cnt ? am : cnt - 1;
    long ar;
    if (isShared)    ar = amc;
    else if (gather) ar = perm[off + amc];
    else             ar = off + amc;
    aP[j] = A + ar * (long)K + kc * 8;
  }
  {
    int c = wid * 64 + lane;
    int row = c >> 2;                        // [0,128)
    int kc = (c & 3) ^ ((row >> 1) & 3);
    bD = wid * 1024;
    gP = Bg + (long)(n0 + row) * K + kc * 8;
    if constexpr (GU) uP = Bu + (long)(n0 + row) * K + kc * 8;
  }

  auto STAGE = [&](int buf, int t) {
    unsigned char* base = lds + buf * BUFB;
    const int koff = t * 32;                 // shorts
    GLOAD_LDS(aP[0] + koff, base + aD[0]);
    GLOAD_LDS(aP[1] + koff, base + aD[1]);
    GLOAD_LDS(gP + koff, base + ABYTES + bD);
    if constexpr (GU) GLOAD_LDS(uP + koff, base + ABYTES + BBYTES + bD);
  };

  f32x4 accg[4][4];
  f32x4 accu[GU ? 4 : 1][GU ? 4 : 1];
#pragma unroll
  for (int a = 0; a < 4; ++a)
#pragma unroll
    for (int b = 0; b < 4; ++b) {
      accg[a][b] = f32x4{0.f, 0.f, 0.f, 0.f};
      if constexpr (GU) accu[a][b] = f32x4{0.f, 0.f, 0.f, 0.f};
    }

  const int r16 = lane & 15, kc4 = lane >> 4;
  const int kq = (kc4 ^ ((r16 >> 1) & 3)) * 8;   // swizzled k-chunk (shorts)
  auto COMPUTE = [&](int buf) {
    const unsigned short* bA = (const unsigned short*)(lds + buf * BUFB);
    const unsigned short* bG = bA + ABYTES / 2;        // +16384 B
    const unsigned short* bU = bG + BBYTES / 2;        // +8192 B more
    bf16x8 af[4], gf[4], uf[4];
#pragma unroll
    for (int mi = 0; mi < 4; ++mi)
      af[mi] = *(const bf16x8*)(bA + (wm + mi * 16 + r16) * 32 + kq);
#pragma unroll
    for (int ni = 0; ni < 4; ++ni) {
      gf[ni] = *(const bf16x8*)(bG + (wn + ni * 16 + r16) * 32 + kq);
      if constexpr (GU)
        uf[ni] = *(const bf16x8*)(bU + (wn + ni * 16 + r16) * 32 + kq);
    }
#pragma unroll
    for (int mi = 0; mi < 4; ++mi)
#pragma unroll
      for (int ni = 0; ni < 4; ++ni) {
        accg[mi][ni] = __builtin_amdgcn_mfma_f32_16x16x32_bf16(af[mi], gf[ni], accg[mi][ni], 0, 0, 0);
        if constexpr (GU)
          accu[mi][ni] = __builtin_amdgcn_mfma_f32_16x16x32_bf16(af[mi], uf[ni], accu[mi][ni], 0, 0, 0);
      }
  };

  // ---- depth-2 pipeline, counted vmcnt (per-wave loads/STAGE: GU=4, else=3) ----
  const int NT = K >> 5;                 // >= 8
  STAGE(0, 0);
  STAGE(1, 1);
  int cur = 0;
  for (int t = 0; t < NT; ++t) {
    if (t + 1 < NT) {
      if constexpr (GU) asm volatile("s_waitcnt vmcnt(4)" ::: "memory");
      else              asm volatile("s_waitcnt vmcnt(3)" ::: "memory");
    } else {
      asm volatile("s_waitcnt vmcnt(0)" ::: "memory");
    }
    __builtin_amdgcn_s_barrier();        // all waves' tile-t loads now visible
    COMPUTE(cur);
    __builtin_amdgcn_s_barrier();        // all waves done reading buf cur
    if (t + 2 < NT) STAGE(cur, t + 2);   // refill freed buffer
    cur ^= 1;
  }

  // epilogue: C layout col=lane&15, row=(lane>>4)*4+reg  [m89-verified]
#pragma unroll
  for (int mi = 0; mi < 4; ++mi)
#pragma unroll
    for (int ni = 0; ni < 4; ++ni)
#pragma unroll
      for (int j = 0; j < 4; ++j) {
        int r = wm + mi * 16 + kc4 * 4 + j;
        int gr = mt * 256 + r;
        if (gr < cnt) {
          int c = n0 + wn + ni * 16 + r16;
          if constexpr (GU) {
            float g = accg[mi][ni][j], u = accu[mi][ni][j];
            float sg = g / (1.f + __expf(-g));       // silu
            unsigned short v = f2bf(sg * u);
            if (isShared) ((unsigned short*)Cs)[(long)gr * ldc + c] = v;
            else          Cr[((long)off + gr) * ldc + c] = v;
          } else {
            if (isShared) ((float*)Cs)[(long)gr * ldc + c] = accg[mi][ni][j];
            else          Cr[((long)off + gr) * ldc + c] = f2bf(accg[mi][ni][j]);
          }
        }
      }
}

// ---------------- final combine: out = x + shared(in d_out) + sum_k w_k*yout ----------------
__global__ __launch_bounds__(256) void combine_kernel(
    const float* __restrict__ x, const float* __restrict__ sh,
    const unsigned short* __restrict__ yout, const float* __restrict__ tw,
    const int* __restrict__ pos, float* __restrict__ out) {
  int n = blockIdx.x;                  // one block per token
  int h4 = threadIdx.x << 2;           // 256 threads * 4 floats = 1024
  float4 xv = *(const float4*)(x + (long)n * HID + h4);
  float4 sv = *(const float4*)(sh + (long)n * HID + h4);   // shared-expert result (read before write)
  float a0 = xv.x + sv.x, a1 = xv.y + sv.y, a2 = xv.z + sv.z, a3 = xv.w + sv.w;
#pragma unroll
  for (int k = 0; k < 4; ++k) {
    float w = tw[n * 4 + k];
    long slot = pos[n * 4 + k];
    ushort4 yv = *(const ushort4*)(yout + slot * HID + h4);
    a0 += w * bf2f(yv.x); a1 += w * bf2f(yv.y);
    a2 += w * bf2f(yv.z); a3 += w * bf2f(yv.w);
  }
  float4 o; o.x = a0; o.y = a1; o.z = a2; o.w = a3;
  *(float4*)(out + (long)n * HID + h4) = o;
}

// ---------------- launch ----------------
extern "C" void kernel_launch(void* const* d_in, const int* in_sizes, int n_in,
                              void* d_out, int out_size, void* d_ws, size_t ws_size,
                              hipStream_t stream) {
  (void)in_sizes; (void)n_in; (void)out_size; (void)ws_size;
  const float* x   = (const float*)d_in[0];
  const float* gw  = (const float*)d_in[1];
  const float* gb  = (const float*)d_in[2];
  const float* Wg  = (const float*)d_in[3];
  const float* Wu  = (const float*)d_in[4];
  const float* Wd  = (const float*)d_in[5];
  const float* Wsg = (const float*)d_in[6];
  const float* Wsu = (const float*)d_in[7];
  const float* Wsd = (const float*)d_in[8];
  float* out = (float*)d_out;

  // ---- workspace layout (big buffers start at 512 KiB; small region ends 262400) ----
  char* w = (char*)d_ws;
  int*   counts   = (int*)(w + 0);                    // 64 B
  int*   cursor   = (int*)(w + 64);                   // 64 B
  int*   offsets  = (int*)(w + 128);                  // 128 B (17 ints)
  int*   topk_idx = (int*)(w + 256);                  // 65536 B
  float* topk_w   = (float*)(w + 256 + 65536);        // 65536 B
  int*   perm     = (int*)(w + 256 + 131072);         // 65536 B
  int*   pos      = (int*)(w + 256 + 196608);         // 65536 B
  size_t o = 524288;                                  // big buffers from 512 KiB
  unsigned short* xb   = (unsigned short*)(w + o); o += (size_t)NTOK * HID * 2;       // 8 MB
  unsigned short* WgB  = (unsigned short*)(w + o); o += (size_t)NEXP * IMO * HID * 2; // 16 MB
  unsigned short* WuB  = (unsigned short*)(w + o); o += (size_t)NEXP * IMO * HID * 2; // 16 MB
  unsigned short* WdB  = (unsigned short*)(w + o); o += (size_t)NEXP * HID * IMO * 2; // 16 MB
  unsigned short* WsgB = (unsigned short*)(w + o); o += (size_t)SHI * HID * 2;        // 2 MB
  unsigned short* WsuB = (unsigned short*)(w + o); o += (size_t)SHI * HID * 2;        // 2 MB
  unsigned short* WsdB = (unsigned short*)(w + o); o += (size_t)HID * SHI * 2;        // 2 MB
  unsigned short* act  = (unsigned short*)(w + o); o += (size_t)NTOK * 4 * IMO * 2;   // 16 MB
  unsigned short* yout = (unsigned short*)(w + o); o += (size_t)NTOK * 4 * HID * 2;   // 32 MB
  unsigned short* sact = (unsigned short*)(w + o); o += (size_t)NTOK * SHI * 2;       // 8 MB
  // total ws use ~118.5 MiB; shared-expert fp32 output goes directly to d_out

  init_counts<<<1, 64, 0, stream>>>(counts);
  gate_kernel<<<NTOK / 4, 256, 0, stream>>>(x, gw, gb, topk_idx, topk_w, counts);
  prefix_kernel<<<1, 64, 0, stream>>>(counts, offsets, cursor);
  scatter_kernel<<<NTOK * 4 / 256, 256, 0, stream>>>(topk_idx, cursor, perm, pos);
  convert_all<<<31744, 256, 0, stream>>>(x, Wg, Wu, Wd, Wsg, Wsu, Wsd,
                                         xb, WgB, WuB, WdB, WsgB, WsuB, WsdB);
  // Level 1: shared gate+up (128 blocks: 16 mt x 8 y) + routed gate+up
  // (1024 slots: e,mt 256 x ny 4), one launch, 512 threads/block.
  gemm_lvl<true><<<128 + 1024, 512, 0, stream>>>(
      xb, WgB, WuB, act, HID, IMO, (long)IMO * HID, counts, offsets, perm, 1,
      xb, WsgB, WsuB, sact, NTOK, HID, SHI, 128);
  // Level 2: shared down (128 blocks) + routed down (2048: e,mt 256 x ny 8).
  gemm_lvl<false><<<128 + 2048, 512, 0, stream>>>(
      act, WdB, nullptr, yout, IMO, HID, (long)HID * IMO, counts, offsets, nullptr, 0,
      sact, WsdB, nullptr, out, NTOK, SHI, HID, 128);
  // out = x + shared + sum_k w_k * yout[pos]
  combine_kernel<<<NTOK, 256, 0, stream>>>(x, out, yout, topk_w, pos, out);
}

// Round 9
// 257.054 us; speedup vs baseline: 3.2420x; 1.0931x over previous
//
#include <hip/hip_runtime.h>
#include <cstdint>

typedef __bf16 bf16x8 __attribute__((ext_vector_type(8)));
typedef float f32x4 __attribute__((ext_vector_type(4)));

#define DI __device__ __forceinline__

constexpr int NTOK = 4096;   // B*S
constexpr int HID  = 1024;
constexpr int IMO  = 512;    // moe intermediate
constexpr int NEXP = 16;
constexpr int SHI  = 1024;   // shared intermediate

// async global->LDS, 16B per lane, wave-uniform LDS base (m97/m193 pattern)
#define GLOAD_LDS(g, l) __builtin_amdgcn_global_load_lds( \
    (const __attribute__((address_space(1))) unsigned int*)(const void*)(g), \
    (__attribute__((address_space(3))) unsigned int*)(void*)(l), 16, 0, 0)

DI unsigned short f2bf(float f) {
  unsigned u = __float_as_uint(f);
  u = (u + 0x7fffu + ((u >> 16) & 1u)) >> 16;   // round-to-nearest-even
  return (unsigned short)u;
}
DI float bf2f(unsigned short b) { return __uint_as_float(((unsigned)b) << 16); }

// ---------------- init / prefix / scatter ----------------
__global__ void init_counts(int* __restrict__ counts) {
  if (threadIdx.x < NEXP) counts[threadIdx.x] = 0;
}

__global__ void prefix_kernel(const int* __restrict__ counts,
                              int* __restrict__ offsets, int* __restrict__ cursor) {
  if (threadIdx.x == 0 && blockIdx.x == 0) {
    int s = 0;
    for (int e = 0; e < NEXP; ++e) { offsets[e] = s; cursor[e] = s; s += counts[e]; }
    offsets[NEXP] = s;
  }
}

__global__ __launch_bounds__(256) void scatter_kernel(
    const int* __restrict__ topk_idx, int* __restrict__ cursor,
    int* __restrict__ perm, int* __restrict__ pos) {
  int i = blockIdx.x * 256 + threadIdx.x;   // over NTOK*4
  int e = topk_idx[i];
  int slot = atomicAdd(&cursor[e], 1);
  perm[slot] = i >> 2;
  pos[i] = slot;
}

// ---------------- gate (fp64 ranking; gw staged in LDS) ----------------
// Round-9: round-4's w4 global loads had 64 distinct 4KB-strided rows per wave
// instruction (64 cachelines/instr -> TA-segment-bound, 82us, VALUBusy 7.8%).
// gw is only 64KB: stage it in LDS once per block, padded row stride 1028 floats
// (4112B, 16B-aligned; bank shift 4/row -> max 2-way aliasing = free). Dot reads
// w via ds_read_b128 (conflict-free) and x via global broadcast (4 segs/instr).
// fp64 ranking/selection logic unchanged from the verified round-4 kernel.
__global__ __launch_bounds__(256) void gate_kernel(
    const float* __restrict__ x, const float* __restrict__ gw,
    const float* __restrict__ gb, int* __restrict__ topk_idx,
    float* __restrict__ topk_w, int* __restrict__ counts) {
  __shared__ float gwl[16 * 1028];          // 65792 B
  const int tid = threadIdx.x;
  // stage gw [16][1024] -> gwl [16][1028] (coalesced read, 16B-aligned writes)
#pragma unroll
  for (int it = 0; it < 16; ++it) {
    int i4 = it * 256 + tid;                // float4 index in [0,4096)
    int row = i4 >> 8, col4 = i4 & 255;
    float4 v = ((const float4*)gw)[i4];
    *(float4*)(gwl + row * 1028 + col4 * 4) = v;
  }
  __syncthreads();

  const int lane = tid & 63;
  const int n = blockIdx.x * 4 + (tid >> 6);
  const int e = lane & 15;          // expert
  const int c = lane >> 4;          // chunk [0,4)
  const int g = e >> 2;             // group [0,4)

  const float4* x4 = (const float4*)(x + (size_t)n * HID + c * 256);
  const float4* w4 = (const float4*)(gwl + e * 1028 + c * 256);

  double acc0 = 0, acc1 = 0, acc2 = 0, acc3 = 0, acc4 = 0, acc5 = 0, acc6 = 0, acc7 = 0;
#pragma unroll
  for (int i = 0; i < 32; ++i) {
    float4 xa = x4[2 * i], xb = x4[2 * i + 1];
    float4 wa = w4[2 * i], wb = w4[2 * i + 1];
    acc0 += (double)xa.x * wa.x; acc1 += (double)xa.y * wa.y;
    acc2 += (double)xa.z * wa.z; acc3 += (double)xa.w * wa.w;
    acc4 += (double)xb.x * wb.x; acc5 += (double)xb.y * wb.y;
    acc6 += (double)xb.z * wb.z; acc7 += (double)xb.w * wb.w;
  }
  double L = ((acc0 + acc1) + (acc2 + acc3)) + ((acc4 + acc5) + (acc6 + acc7));
  L += __shfl_xor(L, 16);
  L += __shfl_xor(L, 32);

  double sig = 1.0 / (1.0 + exp(-L));
  double sfc = sig + (double)gb[e];

  // group score = sum of top-2 sfc within group of 4
  double o1 = __shfl_xor(sfc, 1);
  double hi = fmax(sfc, o1), lo = fmin(sfc, o1);
  double hi2 = __shfl_xor(hi, 2), lo2 = __shfl_xor(lo, 2);
  double gs = fmax(hi, hi2) + fmax(fmin(hi, hi2), fmax(lo, lo2));

  // rank my group among the 4 group scores (stable)
  double gsA = __shfl_xor(gs, 4);
  double gsB = __shfl_xor(gs, 8);
  double gsC = __shfl_xor(gs, 12);
  int grank = 0;
  grank += (gsA > gs || (gsA == gs && (g ^ 1) < g)) ? 1 : 0;
  grank += (gsB > gs || (gsB == gs && (g ^ 2) < g)) ? 1 : 0;
  grank += (gsC > gs || (gsC == gs && (g ^ 3) < g)) ? 1 : 0;
  const bool allowed = grank < 2;

  // expert rank among allowed, stable tie-break by index
  double sv = allowed ? sfc : -1e300;
  int rank = 0;
#pragma unroll
  for (int m = 1; m < 16; ++m) {
    double o = __shfl_xor(sv, m);
    int oe = e ^ m;
    rank += (o > sv || (o == sv && oe < e)) ? 1 : 0;
  }
  const bool chosen = allowed && (rank < 4);

  double t = chosen ? sig : 0.0;
  t += __shfl_xor(t, 1);
  t += __shfl_xor(t, 2);
  t += __shfl_xor(t, 4);
  t += __shfl_xor(t, 8);

  if (chosen && c == 0) {
    topk_idx[n * 4 + rank] = e;
    topk_w[n * 4 + rank] = (float)(sig / (t + 1e-20) * 2.5);
    atomicAdd(&counts[e], 1);
  }
}

// ---------------- fp32 -> bf16 convert (all arrays, one launch) ----------------
__global__ __launch_bounds__(256) void convert_all(
    const float* __restrict__ x, const float* __restrict__ wg,
    const float* __restrict__ wu, const float* __restrict__ wd,
    const float* __restrict__ sg, const float* __restrict__ su,
    const float* __restrict__ sd,
    unsigned short* __restrict__ xb, unsigned short* __restrict__ wgb,
    unsigned short* __restrict__ wub, unsigned short* __restrict__ wdb,
    unsigned short* __restrict__ sgb, unsigned short* __restrict__ sub,
    unsigned short* __restrict__ sdb) {
  long g = (long)blockIdx.x * 256 + threadIdx.x;   // float4 index, total 8126464
  const float* s; unsigned short* d; long o;
  if      (g < 1048576L) { s = x;  d = xb;  o = g; }
  else if (g < 3145728L) { s = wg; d = wgb; o = g - 1048576L; }
  else if (g < 5242880L) { s = wu; d = wub; o = g - 3145728L; }
  else if (g < 7340032L) { s = wd; d = wdb; o = g - 5242880L; }
  else if (g < 7602176L) { s = sg; d = sgb; o = g - 7340032L; }
  else if (g < 7864320L) { s = su; d = sub; o = g - 7602176L; }
  else                   { s = sd; d = sdb; o = g - 7864320L; }
  float4 v = ((const float4*)s)[o];
  ushort4 r;
  r.x = f2bf(v.x); r.y = f2bf(v.y); r.z = f2bf(v.z); r.w = f2bf(v.w);
  ((ushort4*)d)[o] = r;
}

// ---------------- merged bf16 MFMA GEMM level: routed job + shared job ----------------
// BM=256, 8 waves (512 thr), depth-2 counted-vmcnt pipeline, XOR k-swizzle
// (bank-conflict 0). See round-8 notes.
template <bool GU>
__global__ __launch_bounds__(512) void gemm_lvl(
    // routed job
    const unsigned short* __restrict__ Ar, const unsigned short* __restrict__ B0r,
    const unsigned short* __restrict__ B1r, unsigned short* __restrict__ Cr,
    int Kr, int ldcr, long eStrideB,
    const int* __restrict__ counts, const int* __restrict__ offsets,
    const int* __restrict__ perm, int useGather,
    // shared job
    const unsigned short* __restrict__ As, const unsigned short* __restrict__ B0s,
    const unsigned short* __restrict__ B1s, void* __restrict__ Cs,
    int Ms, int Ks, int ldcs, int nShared) {
  const int bx = blockIdx.x;
  const bool isShared = bx < nShared;
  int mt, y, cnt, off = 0, K, ldc;
  const unsigned short *A, *Bg, *Bu = nullptr;
  bool gather = false;
  if (isShared) {
    mt = bx & 15; y = bx >> 4;              // 16 mtiles(256) x ny
    cnt = Ms; K = Ks; ldc = ldcs;
    A = As; Bg = B0s;
    if constexpr (GU) Bu = B1s;
  } else {
    int r = bx - nShared;
    int e = ((r & 7) << 1) | ((r >> 3) & 1); // XCD (r&7) owns experts {2c,2c+1}
    mt = (r >> 4) & 15; y = r >> 8;
    cnt = counts[e]; off = offsets[e];
    if (mt * 256 >= cnt) return;
    K = Kr; ldc = ldcr;
    A = Ar; Bg = B0r + (long)e * eStrideB;
    if constexpr (GU) Bu = B1r + (long)e * eStrideB;
    gather = (useGather != 0);
  }
  const int n0 = y * 128;

  const int tid = threadIdx.x;
  const int lane = tid & 63;
  const int wid = tid >> 6;                  // [0,8)
  const int wm = (wid >> 1) * 64, wn = (wid & 1) * 64;

  constexpr int ABYTES = 16384;              // A region: 256 rows x 32 shorts
  constexpr int BBYTES = 8192;               // each B region: 128 rows x 32 shorts
  constexpr int BUFB = GU ? 32768 : 24576;   // buffer stride (bytes)
  __shared__ __align__(16) unsigned char lds[2 * (GU ? 32768 : 24576)];

  // ---- staging geometry ----
  // A: 1024 chunks(16B) -> 16 DMA instrs, 2/wave; B (g,u): 512 chunks -> 8, 1/wave.
  const unsigned short* aP[2]; const unsigned short* gP; const unsigned short* uP = nullptr;
  int aD[2], bD;
#pragma unroll
  for (int j = 0; j < 2; ++j) {
    int c = (wid * 2 + j) * 64 + lane;
    int row = c >> 2;
    int kc = (c & 3) ^ ((row >> 1) & 3);
    aD[j] = (wid * 2 + j) * 1024;
    int am = mt * 256 + row;
    int amc = am < cnt ? am : cnt - 1;
    long ar;
    if (isShared)    ar = amc;
    else if (gather) ar = perm[off + amc];
    else             ar = off + amc;
    aP[j] = A + ar * (long)K + kc * 8;
  }
  {
    int c = wid * 64 + lane;
    int row = c >> 2;                        // [0,128)
    int kc = (c & 3) ^ ((row >> 1) & 3);
    bD = wid * 1024;
    gP = Bg + (long)(n0 + row) * K + kc * 8;
    if constexpr (GU) uP = Bu + (long)(n0 + row) * K + kc * 8;
  }

  auto STAGE = [&](int buf, int t) {
    unsigned char* base = lds + buf * BUFB;
    const int koff = t * 32;                 // shorts
    GLOAD_LDS(aP[0] + koff, base + aD[0]);
    GLOAD_LDS(aP[1] + koff, base + aD[1]);
    GLOAD_LDS(gP + koff, base + ABYTES + bD);
    if constexpr (GU) GLOAD_LDS(uP + koff, base + ABYTES + BBYTES + bD);
  };

  f32x4 accg[4][4];
  f32x4 accu[GU ? 4 : 1][GU ? 4 : 1];
#pragma unroll
  for (int a = 0; a < 4; ++a)
#pragma unroll
    for (int b = 0; b < 4; ++b) {
      accg[a][b] = f32x4{0.f, 0.f, 0.f, 0.f};
      if constexpr (GU) accu[a][b] = f32x4{0.f, 0.f, 0.f, 0.f};
    }

  const int r16 = lane & 15, kc4 = lane >> 4;
  const int kq = (kc4 ^ ((r16 >> 1) & 3)) * 8;   // swizzled k-chunk (shorts)
  auto COMPUTE = [&](int buf) {
    const unsigned short* bA = (const unsigned short*)(lds + buf * BUFB);
    const unsigned short* bG = bA + ABYTES / 2;        // +16384 B
    const unsigned short* bU = bG + BBYTES / 2;        // +8192 B more
    bf16x8 af[4], gf[4], uf[4];
#pragma unroll
    for (int mi = 0; mi < 4; ++mi)
      af[mi] = *(const bf16x8*)(bA + (wm + mi * 16 + r16) * 32 + kq);
#pragma unroll
    for (int ni = 0; ni < 4; ++ni) {
      gf[ni] = *(const bf16x8*)(bG + (wn + ni * 16 + r16) * 32 + kq);
      if constexpr (GU)
        uf[ni] = *(const bf16x8*)(bU + (wn + ni * 16 + r16) * 32 + kq);
    }
#pragma unroll
    for (int mi = 0; mi < 4; ++mi)
#pragma unroll
      for (int ni = 0; ni < 4; ++ni) {
        accg[mi][ni] = __builtin_amdgcn_mfma_f32_16x16x32_bf16(af[mi], gf[ni], accg[mi][ni], 0, 0, 0);
        if constexpr (GU)
          accu[mi][ni] = __builtin_amdgcn_mfma_f32_16x16x32_bf16(af[mi], uf[ni], accu[mi][ni], 0, 0, 0);
      }
  };

  // ---- depth-2 pipeline, counted vmcnt (per-wave loads/STAGE: GU=4, else=3) ----
  const int NT = K >> 5;                 // >= 8
  STAGE(0, 0);
  STAGE(1, 1);
  int cur = 0;
  for (int t = 0; t < NT; ++t) {
    if (t + 1 < NT) {
      if constexpr (GU) asm volatile("s_waitcnt vmcnt(4)" ::: "memory");
      else              asm volatile("s_waitcnt vmcnt(3)" ::: "memory");
    } else {
      asm volatile("s_waitcnt vmcnt(0)" ::: "memory");
    }
    __builtin_amdgcn_s_barrier();        // all waves' tile-t loads now visible
    COMPUTE(cur);
    __builtin_amdgcn_s_barrier();        // all waves done reading buf cur
    if (t + 2 < NT) STAGE(cur, t + 2);   // refill freed buffer
    cur ^= 1;
  }

  // epilogue: C layout col=lane&15, row=(lane>>4)*4+reg  [m89-verified]
#pragma unroll
  for (int mi = 0; mi < 4; ++mi)
#pragma unroll
    for (int ni = 0; ni < 4; ++ni)
#pragma unroll
      for (int j = 0; j < 4; ++j) {
        int r = wm + mi * 16 + kc4 * 4 + j;
        int gr = mt * 256 + r;
        if (gr < cnt) {
          int c = n0 + wn + ni * 16 + r16;
          if constexpr (GU) {
            float g = accg[mi][ni][j], u = accu[mi][ni][j];
            float sg = g / (1.f + __expf(-g));       // silu
            unsigned short v = f2bf(sg * u);
            if (isShared) ((unsigned short*)Cs)[(long)gr * ldc + c] = v;
            else          Cr[((long)off + gr) * ldc + c] = v;
          } else {
            if (isShared) ((float*)Cs)[(long)gr * ldc + c] = accg[mi][ni][j];
            else          Cr[((long)off + gr) * ldc + c] = f2bf(accg[mi][ni][j]);
          }
        }
      }
}

// ---------------- final combine: out = x + shared(in d_out) + sum_k w_k*yout ----------------
__global__ __launch_bounds__(256) void combine_kernel(
    const float* __restrict__ x, const float* __restrict__ sh,
    const unsigned short* __restrict__ yout, const float* __restrict__ tw,
    const int* __restrict__ pos, float* __restrict__ out) {
  int n = blockIdx.x;                  // one block per token
  int h4 = threadIdx.x << 2;           // 256 threads * 4 floats = 1024
  float4 xv = *(const float4*)(x + (long)n * HID + h4);
  float4 sv = *(const float4*)(sh + (long)n * HID + h4);   // shared-expert result (read before write)
  float a0 = xv.x + sv.x, a1 = xv.y + sv.y, a2 = xv.z + sv.z, a3 = xv.w + sv.w;
#pragma unroll
  for (int k = 0; k < 4; ++k) {
    float w = tw[n * 4 + k];
    long slot = pos[n * 4 + k];
    ushort4 yv = *(const ushort4*)(yout + slot * HID + h4);
    a0 += w * bf2f(yv.x); a1 += w * bf2f(yv.y);
    a2 += w * bf2f(yv.z); a3 += w * bf2f(yv.w);
  }
  float4 o; o.x = a0; o.y = a1; o.z = a2; o.w = a3;
  *(float4*)(out + (long)n * HID + h4) = o;
}

// ---------------- launch ----------------
extern "C" void kernel_launch(void* const* d_in, const int* in_sizes, int n_in,
                              void* d_out, int out_size, void* d_ws, size_t ws_size,
                              hipStream_t stream) {
  (void)in_sizes; (void)n_in; (void)out_size; (void)ws_size;
  const float* x   = (const float*)d_in[0];
  const float* gw  = (const float*)d_in[1];
  const float* gb  = (const float*)d_in[2];
  const float* Wg  = (const float*)d_in[3];
  const float* Wu  = (const float*)d_in[4];
  const float* Wd  = (const float*)d_in[5];
  const float* Wsg = (const float*)d_in[6];
  const float* Wsu = (const float*)d_in[7];
  const float* Wsd = (const float*)d_in[8];
  float* out = (float*)d_out;

  // ---- workspace layout (big buffers start at 512 KiB; small region ends 262400) ----
  char* w = (char*)d_ws;
  int*   counts   = (int*)(w + 0);                    // 64 B
  int*   cursor   = (int*)(w + 64);                   // 64 B
  int*   offsets  = (int*)(w + 128);                  // 128 B (17 ints)
  int*   topk_idx = (int*)(w + 256);                  // 65536 B
  float* topk_w   = (float*)(w + 256 + 65536);        // 65536 B
  int*   perm     = (int*)(w + 256 + 131072);         // 65536 B
  int*   pos      = (int*)(w + 256 + 196608);         // 65536 B
  size_t o = 524288;                                  // big buffers from 512 KiB
  unsigned short* xb   = (unsigned short*)(w + o); o += (size_t)NTOK * HID * 2;       // 8 MB
  unsigned short* WgB  = (unsigned short*)(w + o); o += (size_t)NEXP * IMO * HID * 2; // 16 MB
  unsigned short* WuB  = (unsigned short*)(w + o); o += (size_t)NEXP * IMO * HID * 2; // 16 MB
  unsigned short* WdB  = (unsigned short*)(w + o); o += (size_t)NEXP * HID * IMO * 2; // 16 MB
  unsigned short* WsgB = (unsigned short*)(w + o); o += (size_t)SHI * HID * 2;        // 2 MB
  unsigned short* WsuB = (unsigned short*)(w + o); o += (size_t)SHI * HID * 2;        // 2 MB
  unsigned short* WsdB = (unsigned short*)(w + o); o += (size_t)HID * SHI * 2;        // 2 MB
  unsigned short* act  = (unsigned short*)(w + o); o += (size_t)NTOK * 4 * IMO * 2;   // 16 MB
  unsigned short* yout = (unsigned short*)(w + o); o += (size_t)NTOK * 4 * HID * 2;   // 32 MB
  unsigned short* sact = (unsigned short*)(w + o); o += (size_t)NTOK * SHI * 2;       // 8 MB
  // total ws use ~118.5 MiB; shared-expert fp32 output goes directly to d_out

  init_counts<<<1, 64, 0, stream>>>(counts);
  gate_kernel<<<NTOK / 4, 256, 0, stream>>>(x, gw, gb, topk_idx, topk_w, counts);
  prefix_kernel<<<1, 64, 0, stream>>>(counts, offsets, cursor);
  scatter_kernel<<<NTOK * 4 / 256, 256, 0, stream>>>(topk_idx, cursor, perm, pos);
  convert_all<<<31744, 256, 0, stream>>>(x, Wg, Wu, Wd, Wsg, Wsu, Wsd,
                                         xb, WgB, WuB, WdB, WsgB, WsuB, WsdB);
  // Level 1: shared gate+up (128 blocks: 16 mt x 8 y) + routed gate+up
  // (1024 slots: e,mt 256 x ny 4), one launch, 512 threads/block.
  gemm_lvl<true><<<128 + 1024, 512, 0, stream>>>(
      xb, WgB, WuB, act, HID, IMO, (long)IMO * HID, counts, offsets, perm, 1,
      xb, WsgB, WsuB, sact, NTOK, HID, SHI, 128);
  // Level 2: shared down (128 blocks) + routed down (2048: e,mt 256 x ny 8).
  gemm_lvl<false><<<128 + 2048, 512, 0, stream>>>(
      act, WdB, nullptr, yout, IMO, HID, (long)HID * IMO, counts, offsets, nullptr, 0,
      sact, WsdB, nullptr, out, NTOK, SHI, HID, 128);
  // out = x + shared + sum_k w_k * yout[pos]
  combine_kernel<<<NTOK, 256, 0, stream>>>(x, out, yout, topk_w, pos, out);
}